// Round 1
// baseline (18570.926 us; speedup 1.0000x reference)
//
#include <hip/hip_runtime.h>
#include <hip/hip_bf16.h>

#define N_PTS 65536
#define MCLUS 4096
#define KNN   16
#define C_IN  128
#define C_OUT 256

// ---------------- workspace layout (bytes) ----------------
// 0        : id[4096]              int32   (FPS-selected indices; id[0]=0)
// 16384    : slots[2][64]          u64     (FPS sync mailbox, double-buffered)
// 17408    : nbr[4096*16]          int32
// 279552   : psum [512*256]        f32
// 803840   : psumsq[512*256]       f32
// 1328128  : scale[256]            f32
// 1329152  : shift[256]            f32
#define WS_ID     0
#define WS_SLOTS  16384
#define WS_NBR    17408
#define WS_PSUM   279552
#define WS_PSUMSQ 803840
#define WS_SCALE  1328128
#define WS_SHIFT  1329152

// ---------------- init: reset sync mailbox + id[0] ----------------
__global__ void init_kernel(int* __restrict__ id, unsigned long long* __restrict__ slots) {
    int t = threadIdx.x;
    if (t < 128) slots[t] = 0ull;   // tag 0 never used (steps start at 1)
    if (t == 0) id[0] = 0;
}

// ---------------- FPS: 64 blocks x 1024 threads, 1 point/thread ----------------
// Exact f32, no FMA: d = ((dx*dx + dy*dy) + dz*dz); argmax first-max tie-break.
__global__ __launch_bounds__(1024) void fps_kernel(const float* __restrict__ pos,
                                                   int* __restrict__ id,
                                                   unsigned long long* __restrict__ slots) {
    const int tid = threadIdx.x;
    const int gi  = blockIdx.x * 1024 + tid;
    const float px = pos[gi*3+0], py = pos[gi*3+1], pz = pos[gi*3+2];
    float md = __builtin_inff();
    float cx = pos[0], cy = pos[1], cz = pos[2];   // start point: index 0

    __shared__ unsigned long long lk[16];
    __shared__ float bc[3];
    const int wid = tid >> 6, lane = tid & 63;

    for (int s = 1; s < MCLUS; ++s) {
        float dx = __fsub_rn(px, cx), dy = __fsub_rn(py, cy), dz = __fsub_rn(pz, cz);
        float d  = __fadd_rn(__fadd_rn(__fmul_rn(dx,dx), __fmul_rn(dy,dy)), __fmul_rn(dz,dz));
        md = fminf(md, d);

        // pack: high32 = f32 bits of md (md>=0 so monotonic), low32 = ~idx (tie -> min idx)
        unsigned long long k = ((unsigned long long)__float_as_uint(md) << 32)
                             | (unsigned)(0xFFFFFFFFu - (unsigned)gi);
        #pragma unroll
        for (int off = 32; off > 0; off >>= 1) {
            unsigned long long o = __shfl_down(k, off);
            if (o > k) k = o;
        }
        if (lane == 0) lk[wid] = k;
        __syncthreads();

        if (wid == 0) {
            unsigned long long kk = (lane < 16) ? lk[lane] : 0ull;
            #pragma unroll
            for (int off = 8; off > 0; off >>= 1) {
                unsigned long long o = __shfl_down(kk, off);
                if (o > kk) kk = o;
            }
            const unsigned tag = (unsigned)s & 0xFFFFu;
            if (lane == 0) {
                unsigned idx = 0xFFFFFFFFu - (unsigned)(kk & 0xFFFFFFFFull);
                unsigned long long sv = (kk & 0xFFFFFFFF00000000ull)
                                      | ((unsigned long long)(0xFFFFu - idx) << 16)
                                      | (unsigned long long)tag;
                __hip_atomic_store(&slots[(s & 1)*64 + blockIdx.x], sv,
                                   __ATOMIC_RELEASE, __HIP_MEMORY_SCOPE_AGENT);
            }
            // 64 lanes poll the 64 block slots in parallel
            unsigned long long* sp = &slots[(s & 1)*64 + lane];
            unsigned long long sv;
            do {
                sv = __hip_atomic_load(sp, __ATOMIC_ACQUIRE, __HIP_MEMORY_SCOPE_AGENT);
            } while ((unsigned)(sv & 0xFFFFull) != tag);
            unsigned long long pk = sv >> 16;   // md_bits<<16 | (0xFFFF-idx)
            #pragma unroll
            for (int off = 32; off > 0; off >>= 1) {
                unsigned long long o = __shfl_down(pk, off);
                if (o > pk) pk = o;
            }
            if (lane == 0) {
                unsigned widx = 0xFFFFu - (unsigned)(pk & 0xFFFFull);
                bc[0] = pos[widx*3+0];
                bc[1] = pos[widx*3+1];
                bc[2] = pos[widx*3+2];
                if (blockIdx.x == 0) id[s] = (int)widx;
            }
        }
        __syncthreads();
        cx = bc[0]; cy = bc[1]; cz = bc[2];
    }
}

// ---------------- sub_pos / sub_batch outputs ----------------
__global__ void subout_kernel(const float* __restrict__ pos, const int* __restrict__ batch,
                              const int* __restrict__ id, float* __restrict__ sub_pos,
                              int* __restrict__ sub_batch) {
    int m = blockIdx.x * blockDim.x + threadIdx.x;
    if (m >= MCLUS) return;
    int idx = id[m];
    sub_pos[m*3+0] = pos[idx*3+0];
    sub_pos[m*3+1] = pos[idx*3+1];
    sub_pos[m*3+2] = pos[idx*3+2];
    sub_batch[m] = batch[idx];
}

// ---------------- kNN: one wave per query ----------------
// d2 = (|q|^2 - 2*q.p) + |p|^2, all ops correctly-rounded, no FMA (match reference bits).
__global__ __launch_bounds__(64) void knn_kernel(const float* __restrict__ pos,
                                                 const int* __restrict__ id,
                                                 int* __restrict__ nbr) {
    const int q = blockIdx.x;
    const int lane = threadIdx.x;
    const int qi = id[q];
    const float qx = pos[qi*3+0], qy = pos[qi*3+1], qz = pos[qi*3+2];
    const float nq = __fadd_rn(__fadd_rn(__fmul_rn(qx,qx), __fmul_rn(qy,qy)), __fmul_rn(qz,qz));

    float dl[KNN]; int il[KNN];
    #pragma unroll
    for (int t = 0; t < KNN; ++t) { dl[t] = __builtin_inff(); il[t] = 0x7FFFFFFF; }

    for (int j = lane; j < N_PTS; j += 64) {
        float px = pos[j*3+0], py = pos[j*3+1], pz = pos[j*3+2];
        float npj = __fadd_rn(__fadd_rn(__fmul_rn(px,px), __fmul_rn(py,py)), __fmul_rn(pz,pz));
        float dot = __fadd_rn(__fadd_rn(__fmul_rn(qx,px), __fmul_rn(qy,py)), __fmul_rn(qz,pz));
        float d2  = __fadd_rn(__fsub_rn(nq, __fmul_rn(2.0f, dot)), npj);
        if (d2 < dl[KNN-1] || (d2 == dl[KNN-1] && j < il[KNN-1])) {
            dl[KNN-1] = d2; il[KNN-1] = j;
            #pragma unroll
            for (int t = KNN-1; t > 0; --t) {
                float a = dl[t-1], bq = dl[t];
                int   ai = il[t-1], bi = il[t];
                bool sw = (bq < a) || (bq == a && bi < ai);
                dl[t-1] = sw ? bq : a;  dl[t] = sw ? a : bq;
                il[t-1] = sw ? bi : ai; il[t] = sw ? ai : bi;
            }
        }
    }

    __shared__ float sd[64][KNN];
    __shared__ int   si[64][KNN];
    #pragma unroll
    for (int t = 0; t < KNN; ++t) { sd[lane][t] = dl[t]; si[lane][t] = il[t]; }
    __syncthreads();

    // 64-way merge of sorted lists: 16 rounds of wave-min over heads
    int ptr = 0;
    for (int r = 0; r < KNN; ++r) {
        unsigned long long key = ~0ull;
        if (ptr < KNN) {
            unsigned u = __float_as_uint(sd[lane][ptr]);
            unsigned mu = (u >> 31) ? ~u : (u | 0x80000000u);   // order-preserving (d2 may be <0)
            key = ((unsigned long long)mu << 32) | (unsigned)si[lane][ptr];
        }
        unsigned long long m = key;
        #pragma unroll
        for (int off = 32; off > 0; off >>= 1) {
            unsigned long long o = __shfl_xor(m, off);
            if (o < m) m = o;
        }
        if (key == m) ptr++;
        if (lane == 0) nbr[q*KNN + r] = (int)(m & 0xFFFFFFFFull);
    }
}

// ---------------- BN stats: h = x@W + b, per-channel sum & sumsq ----------------
// 512 blocks x 256 threads; block = 128 rows (2 tiles of 64); thread = 4 channels x 16 rows.
__global__ __launch_bounds__(256) void stats_kernel(const float* __restrict__ x,
                                                    const float* __restrict__ W,
                                                    const float* __restrict__ b,
                                                    float* __restrict__ psum,
                                                    float* __restrict__ psumsq) {
    __shared__ float xl[64*128];     // 32 KiB
    const int tid = threadIdx.x;
    const int cg = (tid & 63) * 4;   // channel group base
    const int rq = tid >> 6;         // row quarter (0..3)
    float s0=0,s1=0,s2v=0,s3=0, q0=0,q1=0,q2=0,q3=0;
    const float4 bv = *(const float4*)&b[cg];

    for (int t = 0; t < 2; ++t) {
        const size_t row0 = (size_t)blockIdx.x*128 + (size_t)t*64;
        __syncthreads();
        for (int i = tid*4; i < 64*128; i += 1024)
            *(float4*)&xl[i] = *(const float4*)&x[row0*128 + i];
        __syncthreads();

        float acc[16][4];
        #pragma unroll
        for (int r = 0; r < 16; ++r) { acc[r][0]=bv.x; acc[r][1]=bv.y; acc[r][2]=bv.z; acc[r][3]=bv.w; }

        for (int k4 = 0; k4 < 32; ++k4) {
            float4 w0 = *(const float4*)&W[(k4*4+0)*256 + cg];
            float4 w1 = *(const float4*)&W[(k4*4+1)*256 + cg];
            float4 w2 = *(const float4*)&W[(k4*4+2)*256 + cg];
            float4 w3 = *(const float4*)&W[(k4*4+3)*256 + cg];
            #pragma unroll
            for (int r = 0; r < 16; ++r) {
                float4 xv = *(float4*)&xl[(rq*16+r)*128 + k4*4];
                acc[r][0] = fmaf(xv.w,w3.x, fmaf(xv.z,w2.x, fmaf(xv.y,w1.x, fmaf(xv.x,w0.x, acc[r][0]))));
                acc[r][1] = fmaf(xv.w,w3.y, fmaf(xv.z,w2.y, fmaf(xv.y,w1.y, fmaf(xv.x,w0.y, acc[r][1]))));
                acc[r][2] = fmaf(xv.w,w3.z, fmaf(xv.z,w2.z, fmaf(xv.y,w1.z, fmaf(xv.x,w0.z, acc[r][2]))));
                acc[r][3] = fmaf(xv.w,w3.w, fmaf(xv.z,w2.w, fmaf(xv.y,w1.w, fmaf(xv.x,w0.w, acc[r][3]))));
            }
        }
        #pragma unroll
        for (int r = 0; r < 16; ++r) {
            s0 += acc[r][0]; q0 = fmaf(acc[r][0],acc[r][0],q0);
            s1 += acc[r][1]; q1 = fmaf(acc[r][1],acc[r][1],q1);
            s2v+= acc[r][2]; q2 = fmaf(acc[r][2],acc[r][2],q2);
            s3 += acc[r][3]; q3 = fmaf(acc[r][3],acc[r][3],q3);
        }
    }
    // in-block reduce across the 4 row-quarters via LDS
    __syncthreads();
    float* red = xl;  // reuse
    red[rq*256 + cg+0] = s0; red[rq*256 + cg+1] = s1; red[rq*256 + cg+2] = s2v; red[rq*256 + cg+3] = s3;
    red[1024 + rq*256 + cg+0] = q0; red[1024 + rq*256 + cg+1] = q1;
    red[1024 + rq*256 + cg+2] = q2; red[1024 + rq*256 + cg+3] = q3;
    __syncthreads();
    if (rq == 0) {
        #pragma unroll
        for (int c = 0; c < 4; ++c) {
            int ch = cg + c;
            float ss = red[ch] + red[256+ch] + red[512+ch] + red[768+ch];
            float qq = red[1024+ch] + red[1280+ch] + red[1536+ch] + red[1792+ch];
            psum  [blockIdx.x*256 + ch] = ss;
            psumsq[blockIdx.x*256 + ch] = qq;
        }
    }
}

__global__ void finalize_kernel(const float* __restrict__ psum, const float* __restrict__ psumsq,
                                const float* __restrict__ gamma, const float* __restrict__ beta,
                                float* __restrict__ scale, float* __restrict__ shift) {
    int c = threadIdx.x;
    float s = 0.f, s2 = 0.f;
    for (int bl = 0; bl < 512; ++bl) { s += psum[bl*256+c]; s2 += psumsq[bl*256+c]; }
    float mu  = s  / 65536.0f;
    float var = s2 / 65536.0f - mu*mu;
    float inv = rsqrtf(var + 1e-5f);
    float sc = gamma[c] * inv;
    scale[c] = sc;
    shift[c] = beta[c] - mu * sc;
}

// ---------------- gather + recompute h rows + pooled BN/ReLU ----------------
// max commutes with monotone per-channel affine+ReLU (min if scale<0).
__global__ __launch_bounds__(256) void out_kernel(const float* __restrict__ x,
                                                  const float* __restrict__ W,
                                                  const float* __restrict__ b,
                                                  const int* __restrict__ nbr,
                                                  const float* __restrict__ scale,
                                                  const float* __restrict__ shift,
                                                  float* __restrict__ out) {
    __shared__ float xl[16*128];   // 8 KiB
    __shared__ int nb[16];
    const int tid = threadIdx.x;
    const int m = blockIdx.x;
    if (tid < 16) nb[tid] = nbr[m*16 + tid];
    __syncthreads();
    for (int i = tid; i < 16*128; i += 256) {
        int r = i >> 7, k = i & 127;
        xl[i] = x[(size_t)nb[r]*128 + k];
    }
    __syncthreads();

    float acc[16];
    const float bias = b[tid];
    #pragma unroll
    for (int r = 0; r < 16; ++r) acc[r] = bias;

    for (int k4 = 0; k4 < 32; ++k4) {
        float w0 = W[(k4*4+0)*256 + tid];
        float w1 = W[(k4*4+1)*256 + tid];
        float w2 = W[(k4*4+2)*256 + tid];
        float w3 = W[(k4*4+3)*256 + tid];
        #pragma unroll
        for (int r = 0; r < 16; ++r) {
            float4 xv = *(float4*)&xl[r*128 + k4*4];
            acc[r] = fmaf(xv.w,w3, fmaf(xv.z,w2, fmaf(xv.y,w1, fmaf(xv.x,w0, acc[r]))));
        }
    }
    const float sc = scale[tid], sh = shift[tid];
    float v = acc[0];
    #pragma unroll
    for (int r = 1; r < 16; ++r) v = (sc >= 0.f) ? fmaxf(v, acc[r]) : fminf(v, acc[r]);
    out[(size_t)m*256 + tid] = fmaxf(fmaf(sc, v, sh), 0.f);
}

// ---------------- launch ----------------
extern "C" void kernel_launch(void* const* d_in, const int* in_sizes, int n_in,
                              void* d_out, int out_size, void* d_ws, size_t ws_size,
                              hipStream_t stream) {
    const float* x     = (const float*)d_in[0];
    const float* pos   = (const float*)d_in[1];
    const int*   batch = (const int*)  d_in[2];
    const float* W     = (const float*)d_in[3];
    const float* b     = (const float*)d_in[4];
    const float* gamma = (const float*)d_in[5];
    const float* beta  = (const float*)d_in[6];

    float* out      = (float*)d_out;
    float* sub_pos  = out + (size_t)MCLUS*C_OUT;
    int*   sub_batch= (int*)(out + (size_t)MCLUS*C_OUT + (size_t)MCLUS*3);

    char* ws = (char*)d_ws;
    int* id                     = (int*)(ws + WS_ID);
    unsigned long long* slots   = (unsigned long long*)(ws + WS_SLOTS);
    int* nbr                    = (int*)(ws + WS_NBR);
    float* psum                 = (float*)(ws + WS_PSUM);
    float* psumsq               = (float*)(ws + WS_PSUMSQ);
    float* scalep               = (float*)(ws + WS_SCALE);
    float* shiftp               = (float*)(ws + WS_SHIFT);

    init_kernel<<<1, 256, 0, stream>>>(id, slots);
    fps_kernel<<<64, 1024, 0, stream>>>(pos, id, slots);
    subout_kernel<<<16, 256, 0, stream>>>(pos, batch, id, sub_pos, sub_batch);
    knn_kernel<<<MCLUS, 64, 0, stream>>>(pos, id, nbr);
    stats_kernel<<<512, 256, 0, stream>>>(x, W, b, psum, psumsq);
    finalize_kernel<<<1, 256, 0, stream>>>(psum, psumsq, gamma, beta, scalep, shiftp);
    out_kernel<<<MCLUS, 256, 0, stream>>>(x, W, b, nbr, scalep, shiftp, out);
}

// Round 2
// 14089.513 us; speedup vs baseline: 1.3181x; 1.3181x over previous
//
#include <hip/hip_runtime.h>
#include <hip/hip_bf16.h>

#define N_PTS 65536
#define MCLUS 4096
#define KNN   16
#define C_IN  128
#define C_OUT 256

// ---------------- workspace layout (bytes) ----------------
// 0        : id[4096]                 int32
// 16384    : slots[2][4][64]          u64   (FPS mailbox: parity x word x block)
// 20480    : nbr[4096*16]             int32
// 282624   : psum [512*256]           f32
// 806912   : psumsq[512*256]          f32
// 1331200  : scale[256]               f32
// 1332224  : shift[256]               f32
#define WS_ID     0
#define WS_SLOTS  16384
#define WS_NBR    20480
#define WS_PSUM   282624
#define WS_PSUMSQ 806912
#define WS_SCALE  1331200
#define WS_SHIFT  1332224

// ---------------- init: reset sync mailbox + id[0] ----------------
__global__ void init_kernel(int* __restrict__ id, unsigned long long* __restrict__ slots) {
    int t = threadIdx.x;
    if (t < 512) slots[t] = 0ull;   // tag 0 never used (steps start at 1)
    if (t == 0) id[0] = 0;
}

// ---------------- FPS: 64 blocks x 64 threads (1 wave), 16 points/thread ----------
// All state in VGPRs. Mailbox carries candidate (min_d, idx) AND its position in
// self-tagged u64 words; relaxed agent-scope atomics (payload in-word, double-buffered
// by step parity, block skew provably <=1 step -> no fences needed).
// Exact f32, no FMA: d = ((dx*dx + dy*dy) + dz*dz); argmax first-max tie-break.
__global__ __launch_bounds__(64) void fps_kernel(const float* __restrict__ pos,
                                                 int* __restrict__ id,
                                                 unsigned long long* __restrict__ slots) {
    const int lane = threadIdx.x;
    const int blk  = blockIdx.x;
    // point index for element e: blk*1024 + e*64 + lane
    float px[16], py[16], pz[16], md[16];
    #pragma unroll
    for (int e = 0; e < 16; ++e) {
        int gi = blk*1024 + e*64 + lane;
        px[e] = pos[gi*3+0]; py[e] = pos[gi*3+1]; pz[e] = pos[gi*3+2];
        md[e] = __builtin_inff();
    }
    float cx = pos[0], cy = pos[1], cz = pos[2];

    for (int s = 1; s < MCLUS; ++s) {
        // ---- local update + thread-local argmax (positions tracked via select) ----
        unsigned long long bestk = 0ull;
        float bpx = 0.f, bpy = 0.f, bpz = 0.f;
        #pragma unroll
        for (int e = 0; e < 16; ++e) {
            float dx = __fsub_rn(px[e], cx), dy = __fsub_rn(py[e], cy), dz = __fsub_rn(pz[e], cz);
            float d  = __fadd_rn(__fadd_rn(__fmul_rn(dx,dx), __fmul_rn(dy,dy)), __fmul_rn(dz,dz));
            md[e] = fminf(md[e], d);
            unsigned gi = (unsigned)(blk*1024 + e*64 + lane);
            unsigned long long key = ((unsigned long long)__float_as_uint(md[e]) << 32)
                                   | (0xFFFFFFFFu - gi);     // tie -> min idx
            bool better = key > bestk;
            bestk = better ? key : bestk;
            bpx = better ? px[e] : bpx;
            bpy = better ? py[e] : bpy;
            bpz = better ? pz[e] : bpz;
        }

        // ---- in-wave reduce: block candidate ----
        unsigned long long kb = bestk;
        #pragma unroll
        for (int off = 32; off > 0; off >>= 1) {
            unsigned long long o = __shfl_xor(kb, off);
            if (o > kb) kb = o;
        }
        unsigned long long ball = __ballot(bestk == kb);   // key unique (contains idx)
        int src = __ffsll(ball) - 1;
        float wpx = __shfl(bpx, src), wpy = __shfl(bpy, src), wpz = __shfl(bpz, src);

        // ---- publish block candidate: 4 self-tagged words, relaxed agent scope ----
        const unsigned long long tag = (unsigned long long)(s & 0xFFFF);
        unsigned long long* base = &slots[(unsigned)(s & 1) * 256];
        if (lane == 0) {
            unsigned md_bits = (unsigned)(kb >> 32);
            unsigned idx     = 0xFFFFFFFFu - (unsigned)(kb & 0xFFFFFFFFull);  // < 65536
            unsigned long long w0 = ((unsigned long long)md_bits << 32)
                                  | ((unsigned long long)(0xFFFFu - idx) << 16) | tag;
            unsigned long long w1 = ((unsigned long long)__float_as_uint(wpx) << 32) | tag;
            unsigned long long w2 = ((unsigned long long)__float_as_uint(wpy) << 32) | tag;
            unsigned long long w3 = ((unsigned long long)__float_as_uint(wpz) << 32) | tag;
            __hip_atomic_store(&base[0*64 + blk], w0, __ATOMIC_RELAXED, __HIP_MEMORY_SCOPE_AGENT);
            __hip_atomic_store(&base[1*64 + blk], w1, __ATOMIC_RELAXED, __HIP_MEMORY_SCOPE_AGENT);
            __hip_atomic_store(&base[2*64 + blk], w2, __ATOMIC_RELAXED, __HIP_MEMORY_SCOPE_AGENT);
            __hip_atomic_store(&base[3*64 + blk], w3, __ATOMIC_RELAXED, __HIP_MEMORY_SCOPE_AGENT);
        }

        // ---- lane l polls block l's words (each self-tagged) ----
        unsigned long long w0, w1, w2, w3;
        do { w0 = __hip_atomic_load(&base[0*64 + lane], __ATOMIC_RELAXED, __HIP_MEMORY_SCOPE_AGENT);
        } while ((unsigned)(w0 & 0xFFFFull) != (unsigned)tag);
        do { w1 = __hip_atomic_load(&base[1*64 + lane], __ATOMIC_RELAXED, __HIP_MEMORY_SCOPE_AGENT);
        } while ((unsigned)(w1 & 0xFFFFull) != (unsigned)tag);
        do { w2 = __hip_atomic_load(&base[2*64 + lane], __ATOMIC_RELAXED, __HIP_MEMORY_SCOPE_AGENT);
        } while ((unsigned)(w2 & 0xFFFFull) != (unsigned)tag);
        do { w3 = __hip_atomic_load(&base[3*64 + lane], __ATOMIC_RELAXED, __HIP_MEMORY_SCOPE_AGENT);
        } while ((unsigned)(w3 & 0xFFFFull) != (unsigned)tag);

        // ---- cross-block reduce: key = md(32) | inv_idx(16), 48 bits ----
        unsigned long long k = w0 >> 16;
        unsigned long long kmax = k;
        #pragma unroll
        for (int off = 32; off > 0; off >>= 1) {
            unsigned long long o = __shfl_xor(kmax, off);
            if (o > kmax) kmax = o;
        }
        unsigned long long b2 = __ballot(k == kmax);       // unique (contains idx)
        int src2 = __ffsll(b2) - 1;
        cx = __shfl(__uint_as_float((unsigned)(w1 >> 32)), src2);
        cy = __shfl(__uint_as_float((unsigned)(w2 >> 32)), src2);
        cz = __shfl(__uint_as_float((unsigned)(w3 >> 32)), src2);
        if (blk == 0 && lane == 0) {
            unsigned widx = 0xFFFFu - (unsigned)(kmax & 0xFFFFull);
            id[s] = (int)widx;
        }
    }
}

// ---------------- sub_pos / sub_batch outputs ----------------
__global__ void subout_kernel(const float* __restrict__ pos, const int* __restrict__ batch,
                              const int* __restrict__ id, float* __restrict__ sub_pos,
                              int* __restrict__ sub_batch) {
    int m = blockIdx.x * blockDim.x + threadIdx.x;
    if (m >= MCLUS) return;
    int idx = id[m];
    sub_pos[m*3+0] = pos[idx*3+0];
    sub_pos[m*3+1] = pos[idx*3+1];
    sub_pos[m*3+2] = pos[idx*3+2];
    sub_batch[m] = batch[idx];
}

// ---------------- kNN: one wave per query ----------------
// d2 = (|q|^2 - 2*q.p) + |p|^2, all ops correctly-rounded, no FMA (match reference bits).
__global__ __launch_bounds__(64) void knn_kernel(const float* __restrict__ pos,
                                                 const int* __restrict__ id,
                                                 int* __restrict__ nbr) {
    const int q = blockIdx.x;
    const int lane = threadIdx.x;
    const int qi = id[q];
    const float qx = pos[qi*3+0], qy = pos[qi*3+1], qz = pos[qi*3+2];
    const float nq = __fadd_rn(__fadd_rn(__fmul_rn(qx,qx), __fmul_rn(qy,qy)), __fmul_rn(qz,qz));

    float dl[KNN]; int il[KNN];
    #pragma unroll
    for (int t = 0; t < KNN; ++t) { dl[t] = __builtin_inff(); il[t] = 0x7FFFFFFF; }

    for (int j = lane; j < N_PTS; j += 64) {
        float px = pos[j*3+0], py = pos[j*3+1], pz = pos[j*3+2];
        float npj = __fadd_rn(__fadd_rn(__fmul_rn(px,px), __fmul_rn(py,py)), __fmul_rn(pz,pz));
        float dot = __fadd_rn(__fadd_rn(__fmul_rn(qx,px), __fmul_rn(qy,py)), __fmul_rn(qz,pz));
        float d2  = __fadd_rn(__fsub_rn(nq, __fmul_rn(2.0f, dot)), npj);
        if (d2 < dl[KNN-1] || (d2 == dl[KNN-1] && j < il[KNN-1])) {
            dl[KNN-1] = d2; il[KNN-1] = j;
            #pragma unroll
            for (int t = KNN-1; t > 0; --t) {
                float a = dl[t-1], bq = dl[t];
                int   ai = il[t-1], bi = il[t];
                bool sw = (bq < a) || (bq == a && bi < ai);
                dl[t-1] = sw ? bq : a;  dl[t] = sw ? a : bq;
                il[t-1] = sw ? bi : ai; il[t] = sw ? ai : bi;
            }
        }
    }

    __shared__ float sd[64][KNN];
    __shared__ int   si[64][KNN];
    #pragma unroll
    for (int t = 0; t < KNN; ++t) { sd[lane][t] = dl[t]; si[lane][t] = il[t]; }
    __syncthreads();

    // 64-way merge of sorted lists: 16 rounds of wave-min over heads
    int ptr = 0;
    for (int r = 0; r < KNN; ++r) {
        unsigned long long key = ~0ull;
        if (ptr < KNN) {
            unsigned u = __float_as_uint(sd[lane][ptr]);
            unsigned mu = (u >> 31) ? ~u : (u | 0x80000000u);   // order-preserving
            key = ((unsigned long long)mu << 32) | (unsigned)si[lane][ptr];
        }
        unsigned long long m = key;
        #pragma unroll
        for (int off = 32; off > 0; off >>= 1) {
            unsigned long long o = __shfl_xor(m, off);
            if (o < m) m = o;
        }
        if (key == m) ptr++;
        if (lane == 0) nbr[q*KNN + r] = (int)(m & 0xFFFFFFFFull);
    }
}

// ---------------- BN stats: h = x@W + b, per-channel sum & sumsq ----------------
__global__ __launch_bounds__(256) void stats_kernel(const float* __restrict__ x,
                                                    const float* __restrict__ W,
                                                    const float* __restrict__ b,
                                                    float* __restrict__ psum,
                                                    float* __restrict__ psumsq) {
    __shared__ float xl[64*128];     // 32 KiB
    const int tid = threadIdx.x;
    const int cg = (tid & 63) * 4;   // channel group base
    const int rq = tid >> 6;         // row quarter (0..3)
    float s0=0,s1=0,s2v=0,s3=0, q0=0,q1=0,q2=0,q3=0;
    const float4 bv = *(const float4*)&b[cg];

    for (int t = 0; t < 2; ++t) {
        const size_t row0 = (size_t)blockIdx.x*128 + (size_t)t*64;
        __syncthreads();
        for (int i = tid*4; i < 64*128; i += 1024)
            *(float4*)&xl[i] = *(const float4*)&x[row0*128 + i];
        __syncthreads();

        float acc[16][4];
        #pragma unroll
        for (int r = 0; r < 16; ++r) { acc[r][0]=bv.x; acc[r][1]=bv.y; acc[r][2]=bv.z; acc[r][3]=bv.w; }

        for (int k4 = 0; k4 < 32; ++k4) {
            float4 w0 = *(const float4*)&W[(k4*4+0)*256 + cg];
            float4 w1 = *(const float4*)&W[(k4*4+1)*256 + cg];
            float4 w2 = *(const float4*)&W[(k4*4+2)*256 + cg];
            float4 w3 = *(const float4*)&W[(k4*4+3)*256 + cg];
            #pragma unroll
            for (int r = 0; r < 16; ++r) {
                float4 xv = *(float4*)&xl[(rq*16+r)*128 + k4*4];
                acc[r][0] = fmaf(xv.w,w3.x, fmaf(xv.z,w2.x, fmaf(xv.y,w1.x, fmaf(xv.x,w0.x, acc[r][0]))));
                acc[r][1] = fmaf(xv.w,w3.y, fmaf(xv.z,w2.y, fmaf(xv.y,w1.y, fmaf(xv.x,w0.y, acc[r][1]))));
                acc[r][2] = fmaf(xv.w,w3.z, fmaf(xv.z,w2.z, fmaf(xv.y,w1.z, fmaf(xv.x,w0.z, acc[r][2]))));
                acc[r][3] = fmaf(xv.w,w3.w, fmaf(xv.z,w2.w, fmaf(xv.y,w1.w, fmaf(xv.x,w0.w, acc[r][3]))));
            }
        }
        #pragma unroll
        for (int r = 0; r < 16; ++r) {
            s0 += acc[r][0]; q0 = fmaf(acc[r][0],acc[r][0],q0);
            s1 += acc[r][1]; q1 = fmaf(acc[r][1],acc[r][1],q1);
            s2v+= acc[r][2]; q2 = fmaf(acc[r][2],acc[r][2],q2);
            s3 += acc[r][3]; q3 = fmaf(acc[r][3],acc[r][3],q3);
        }
    }
    __syncthreads();
    float* red = xl;  // reuse
    red[rq*256 + cg+0] = s0; red[rq*256 + cg+1] = s1; red[rq*256 + cg+2] = s2v; red[rq*256 + cg+3] = s3;
    red[1024 + rq*256 + cg+0] = q0; red[1024 + rq*256 + cg+1] = q1;
    red[1024 + rq*256 + cg+2] = q2; red[1024 + rq*256 + cg+3] = q3;
    __syncthreads();
    if (rq == 0) {
        #pragma unroll
        for (int c = 0; c < 4; ++c) {
            int ch = cg + c;
            float ss = red[ch] + red[256+ch] + red[512+ch] + red[768+ch];
            float qq = red[1024+ch] + red[1280+ch] + red[1536+ch] + red[1792+ch];
            psum  [blockIdx.x*256 + ch] = ss;
            psumsq[blockIdx.x*256 + ch] = qq;
        }
    }
}

__global__ void finalize_kernel(const float* __restrict__ psum, const float* __restrict__ psumsq,
                                const float* __restrict__ gamma, const float* __restrict__ beta,
                                float* __restrict__ scale, float* __restrict__ shift) {
    int c = threadIdx.x;
    float s = 0.f, s2 = 0.f;
    for (int bl = 0; bl < 512; ++bl) { s += psum[bl*256+c]; s2 += psumsq[bl*256+c]; }
    float mu  = s  / 65536.0f;
    float var = s2 / 65536.0f - mu*mu;
    float inv = rsqrtf(var + 1e-5f);
    float sc = gamma[c] * inv;
    scale[c] = sc;
    shift[c] = beta[c] - mu * sc;
}

// ---------------- gather + recompute h rows + pooled BN/ReLU ----------------
__global__ __launch_bounds__(256) void out_kernel(const float* __restrict__ x,
                                                  const float* __restrict__ W,
                                                  const float* __restrict__ b,
                                                  const int* __restrict__ nbr,
                                                  const float* __restrict__ scale,
                                                  const float* __restrict__ shift,
                                                  float* __restrict__ out) {
    __shared__ float xl[16*128];   // 8 KiB
    __shared__ int nb[16];
    const int tid = threadIdx.x;
    const int m = blockIdx.x;
    if (tid < 16) nb[tid] = nbr[m*16 + tid];
    __syncthreads();
    for (int i = tid; i < 16*128; i += 256) {
        int r = i >> 7, k = i & 127;
        xl[i] = x[(size_t)nb[r]*128 + k];
    }
    __syncthreads();

    float acc[16];
    const float bias = b[tid];
    #pragma unroll
    for (int r = 0; r < 16; ++r) acc[r] = bias;

    for (int k4 = 0; k4 < 32; ++k4) {
        float w0 = W[(k4*4+0)*256 + tid];
        float w1 = W[(k4*4+1)*256 + tid];
        float w2 = W[(k4*4+2)*256 + tid];
        float w3 = W[(k4*4+3)*256 + tid];
        #pragma unroll
        for (int r = 0; r < 16; ++r) {
            float4 xv = *(float4*)&xl[r*128 + k4*4];
            acc[r] = fmaf(xv.w,w3, fmaf(xv.z,w2, fmaf(xv.y,w1, fmaf(xv.x,w0, acc[r]))));
        }
    }
    const float sc = scale[tid], sh = shift[tid];
    float v = acc[0];
    #pragma unroll
    for (int r = 1; r < 16; ++r) v = (sc >= 0.f) ? fmaxf(v, acc[r]) : fminf(v, acc[r]);
    out[(size_t)m*256 + tid] = fmaxf(fmaf(sc, v, sh), 0.f);
}

// ---------------- launch ----------------
extern "C" void kernel_launch(void* const* d_in, const int* in_sizes, int n_in,
                              void* d_out, int out_size, void* d_ws, size_t ws_size,
                              hipStream_t stream) {
    const float* x     = (const float*)d_in[0];
    const float* pos   = (const float*)d_in[1];
    const int*   batch = (const int*)  d_in[2];
    const float* W     = (const float*)d_in[3];
    const float* b     = (const float*)d_in[4];
    const float* gamma = (const float*)d_in[5];
    const float* beta  = (const float*)d_in[6];

    float* out      = (float*)d_out;
    float* sub_pos  = out + (size_t)MCLUS*C_OUT;
    int*   sub_batch= (int*)(out + (size_t)MCLUS*C_OUT + (size_t)MCLUS*3);

    char* ws = (char*)d_ws;
    int* id                     = (int*)(ws + WS_ID);
    unsigned long long* slots   = (unsigned long long*)(ws + WS_SLOTS);
    int* nbr                    = (int*)(ws + WS_NBR);
    float* psum                 = (float*)(ws + WS_PSUM);
    float* psumsq               = (float*)(ws + WS_PSUMSQ);
    float* scalep               = (float*)(ws + WS_SCALE);
    float* shiftp               = (float*)(ws + WS_SHIFT);

    init_kernel<<<1, 512, 0, stream>>>(id, slots);
    fps_kernel<<<64, 64, 0, stream>>>(pos, id, slots);
    subout_kernel<<<16, 256, 0, stream>>>(pos, batch, id, sub_pos, sub_batch);
    knn_kernel<<<MCLUS, 64, 0, stream>>>(pos, id, nbr);
    stats_kernel<<<512, 256, 0, stream>>>(x, W, b, psum, psumsq);
    finalize_kernel<<<1, 256, 0, stream>>>(psum, psumsq, gamma, beta, scalep, shiftp);
    out_kernel<<<MCLUS, 256, 0, stream>>>(x, W, b, nbr, scalep, shiftp, out);
}

// Round 3
// 9218.180 us; speedup vs baseline: 2.0146x; 1.5284x over previous
//
#include <hip/hip_runtime.h>
#include <hip/hip_bf16.h>

#define N_PTS 65536
#define MCLUS 4096
#define KNN   16
#define C_IN  128
#define C_OUT 256

// ---------------- workspace layout (bytes) ----------------
// 0        : id[4096]                 int32
// 16384    : slots[2][64][8]          u64   (FPS mailbox: parity x block x word, 64B/block)
// 24576    : nbr[4096*16]             int32
// 286720   : psum [512*256]           f32
// 811008   : psumsq[512*256]          f32
// 1335296  : scale[256]               f32
// 1336320  : shift[256]               f32
#define WS_ID     0
#define WS_SLOTS  16384
#define WS_NBR    24576
#define WS_PSUM   286720
#define WS_PSUMSQ 811008
#define WS_SCALE  1335296
#define WS_SHIFT  1336320

// ---------------- init: reset sync mailbox + id[0] ----------------
__global__ void init_kernel(int* __restrict__ id, unsigned long long* __restrict__ slots) {
    int t = threadIdx.x;
    if (t < 1024) slots[t] = 0ull;   // tag 0 never used (steps start at 1)
    if (t == 0) id[0] = 0;
}

// ---------------- FPS: 64 blocks x 64 threads (1 wave), 16 points/thread ----------
// All state in VGPRs. Mailbox carries candidate (min_d, idx) AND its position in
// self-tagged u64 words; relaxed agent-scope atomics (payload in-word, double-buffered
// by step parity, block skew provably <=1 step -> no fences needed).
// Critical path: publish store visibility + ONE combined 4-word poll round trip.
// Exact f32, no FMA: d = ((dx*dx + dy*dy) + dz*dz); argmax first-max tie-break.
__global__ __launch_bounds__(64) void fps_kernel(const float* __restrict__ pos,
                                                 int* __restrict__ id,
                                                 unsigned long long* __restrict__ slots) {
    const int lane = threadIdx.x;
    const int blk  = blockIdx.x;
    // point index for element e: blk*1024 + e*64 + lane
    float px[16], py[16], pz[16], md[16];
    #pragma unroll
    for (int e = 0; e < 16; ++e) {
        int gi = blk*1024 + e*64 + lane;
        px[e] = pos[gi*3+0]; py[e] = pos[gi*3+1]; pz[e] = pos[gi*3+2];
        md[e] = __builtin_inff();
    }
    float cx = pos[0], cy = pos[1], cz = pos[2];

    for (int s = 1; s < MCLUS; ++s) {
        // ---- local update + thread-local argmax (positions tracked via select) ----
        unsigned long long bestk = 0ull;
        float bpx = 0.f, bpy = 0.f, bpz = 0.f;
        #pragma unroll
        for (int e = 0; e < 16; ++e) {
            float dx = __fsub_rn(px[e], cx), dy = __fsub_rn(py[e], cy), dz = __fsub_rn(pz[e], cz);
            float d  = __fadd_rn(__fadd_rn(__fmul_rn(dx,dx), __fmul_rn(dy,dy)), __fmul_rn(dz,dz));
            md[e] = fminf(md[e], d);
            unsigned gi = (unsigned)(blk*1024 + e*64 + lane);
            unsigned long long key = ((unsigned long long)__float_as_uint(md[e]) << 32)
                                   | (0xFFFFFFFFu - gi);     // tie -> min idx
            bool better = key > bestk;
            bestk = better ? key : bestk;
            bpx = better ? px[e] : bpx;
            bpy = better ? py[e] : bpy;
            bpz = better ? pz[e] : bpz;
        }

        // ---- in-wave butterfly reduce: all lanes end with block winner ----
        unsigned long long kb = bestk;
        #pragma unroll
        for (int off = 32; off > 0; off >>= 1) {
            unsigned long long o = __shfl_xor(kb, off);
            if (o > kb) kb = o;
        }
        unsigned long long ball = __ballot(bestk == kb);   // key unique (contains idx)
        int src = __ffsll(ball) - 1;
        float wpx = __shfl(bpx, src), wpy = __shfl(bpy, src), wpz = __shfl(bpz, src);

        // ---- publish: lanes 0-3 store the 4 self-tagged words in ONE instruction ----
        const unsigned long long tag = (unsigned long long)(s & 0xFFFF);
        unsigned long long* base = &slots[(unsigned)(s & 1) * 512];   // [parity][64][8]
        {
            unsigned md_bits = (unsigned)(kb >> 32);
            unsigned idx     = 0xFFFFFFFFu - (unsigned)(kb & 0xFFFFFFFFull);  // < 65536
            unsigned long long w0 = ((unsigned long long)md_bits << 32)
                                  | ((unsigned long long)(0xFFFFu - idx) << 16) | tag;
            unsigned long long w1 = ((unsigned long long)__float_as_uint(wpx) << 32) | tag;
            unsigned long long w2 = ((unsigned long long)__float_as_uint(wpy) << 32) | tag;
            unsigned long long w3 = ((unsigned long long)__float_as_uint(wpz) << 32) | tag;
            unsigned long long wv = (lane == 0) ? w0 : (lane == 1) ? w1 : (lane == 2) ? w2 : w3;
            if (lane < 4)
                __hip_atomic_store(&base[(unsigned)blk*8 + (unsigned)lane], wv,
                                   __ATOMIC_RELAXED, __HIP_MEMORY_SCOPE_AGENT);
        }

        // ---- lane l polls block l's 4 words in ONE combined loop (parallel loads) ----
        unsigned long long* bp = &base[(unsigned)lane * 8];
        unsigned long long w0, w1, w2, w3;
        for (;;) {
            w0 = __hip_atomic_load(&bp[0], __ATOMIC_RELAXED, __HIP_MEMORY_SCOPE_AGENT);
            w1 = __hip_atomic_load(&bp[1], __ATOMIC_RELAXED, __HIP_MEMORY_SCOPE_AGENT);
            w2 = __hip_atomic_load(&bp[2], __ATOMIC_RELAXED, __HIP_MEMORY_SCOPE_AGENT);
            w3 = __hip_atomic_load(&bp[3], __ATOMIC_RELAXED, __HIP_MEMORY_SCOPE_AGENT);
            unsigned long long bad = ((w0 ^ tag) | (w1 ^ tag) | (w2 ^ tag) | (w3 ^ tag)) & 0xFFFFull;
            if (bad == 0ull) break;
        }

        // ---- cross-block reduce: key = md(32) | inv_idx(16), 48 bits ----
        unsigned long long k = w0 >> 16;
        unsigned long long kmax = k;
        #pragma unroll
        for (int off = 32; off > 0; off >>= 1) {
            unsigned long long o = __shfl_xor(kmax, off);
            if (o > kmax) kmax = o;
        }
        unsigned long long b2 = __ballot(k == kmax);       // unique (contains idx)
        int src2 = __ffsll(b2) - 1;
        cx = __shfl(__uint_as_float((unsigned)(w1 >> 32)), src2);
        cy = __shfl(__uint_as_float((unsigned)(w2 >> 32)), src2);
        cz = __shfl(__uint_as_float((unsigned)(w3 >> 32)), src2);
        if (blk == 0 && lane == 0) {
            unsigned widx = 0xFFFFu - (unsigned)(kmax & 0xFFFFull);
            id[s] = (int)widx;
        }
    }
}

// ---------------- sub_pos / sub_batch outputs ----------------
__global__ void subout_kernel(const float* __restrict__ pos, const int* __restrict__ batch,
                              const int* __restrict__ id, float* __restrict__ sub_pos,
                              int* __restrict__ sub_batch) {
    int m = blockIdx.x * blockDim.x + threadIdx.x;
    if (m >= MCLUS) return;
    int idx = id[m];
    sub_pos[m*3+0] = pos[idx*3+0];
    sub_pos[m*3+1] = pos[idx*3+1];
    sub_pos[m*3+2] = pos[idx*3+2];
    sub_batch[m] = batch[idx];
}

// ---------------- kNN: one wave per query ----------------
// d2 = (|q|^2 - 2*q.p) + |p|^2, all ops correctly-rounded, no FMA (match reference bits).
__global__ __launch_bounds__(64) void knn_kernel(const float* __restrict__ pos,
                                                 const int* __restrict__ id,
                                                 int* __restrict__ nbr) {
    const int q = blockIdx.x;
    const int lane = threadIdx.x;
    const int qi = id[q];
    const float qx = pos[qi*3+0], qy = pos[qi*3+1], qz = pos[qi*3+2];
    const float nq = __fadd_rn(__fadd_rn(__fmul_rn(qx,qx), __fmul_rn(qy,qy)), __fmul_rn(qz,qz));

    float dl[KNN]; int il[KNN];
    #pragma unroll
    for (int t = 0; t < KNN; ++t) { dl[t] = __builtin_inff(); il[t] = 0x7FFFFFFF; }

    for (int j = lane; j < N_PTS; j += 64) {
        float px = pos[j*3+0], py = pos[j*3+1], pz = pos[j*3+2];
        float npj = __fadd_rn(__fadd_rn(__fmul_rn(px,px), __fmul_rn(py,py)), __fmul_rn(pz,pz));
        float dot = __fadd_rn(__fadd_rn(__fmul_rn(qx,px), __fmul_rn(qy,py)), __fmul_rn(qz,pz));
        float d2  = __fadd_rn(__fsub_rn(nq, __fmul_rn(2.0f, dot)), npj);
        if (d2 < dl[KNN-1] || (d2 == dl[KNN-1] && j < il[KNN-1])) {
            dl[KNN-1] = d2; il[KNN-1] = j;
            #pragma unroll
            for (int t = KNN-1; t > 0; --t) {
                float a = dl[t-1], bq = dl[t];
                int   ai = il[t-1], bi = il[t];
                bool sw = (bq < a) || (bq == a && bi < ai);
                dl[t-1] = sw ? bq : a;  dl[t] = sw ? a : bq;
                il[t-1] = sw ? bi : ai; il[t] = sw ? ai : bi;
            }
        }
    }

    __shared__ float sd[64][KNN];
    __shared__ int   si[64][KNN];
    #pragma unroll
    for (int t = 0; t < KNN; ++t) { sd[lane][t] = dl[t]; si[lane][t] = il[t]; }
    __syncthreads();

    // 64-way merge of sorted lists: 16 rounds of wave-min over heads
    int ptr = 0;
    for (int r = 0; r < KNN; ++r) {
        unsigned long long key = ~0ull;
        if (ptr < KNN) {
            unsigned u = __float_as_uint(sd[lane][ptr]);
            unsigned mu = (u >> 31) ? ~u : (u | 0x80000000u);   // order-preserving
            key = ((unsigned long long)mu << 32) | (unsigned)si[lane][ptr];
        }
        unsigned long long m = key;
        #pragma unroll
        for (int off = 32; off > 0; off >>= 1) {
            unsigned long long o = __shfl_xor(m, off);
            if (o < m) m = o;
        }
        if (key == m) ptr++;
        if (lane == 0) nbr[q*KNN + r] = (int)(m & 0xFFFFFFFFull);
    }
}

// ---------------- BN stats: h = x@W + b, per-channel sum & sumsq ----------------
__global__ __launch_bounds__(256) void stats_kernel(const float* __restrict__ x,
                                                    const float* __restrict__ W,
                                                    const float* __restrict__ b,
                                                    float* __restrict__ psum,
                                                    float* __restrict__ psumsq) {
    __shared__ float xl[64*128];     // 32 KiB
    const int tid = threadIdx.x;
    const int cg = (tid & 63) * 4;   // channel group base
    const int rq = tid >> 6;         // row quarter (0..3)
    float s0=0,s1=0,s2v=0,s3=0, q0=0,q1=0,q2=0,q3=0;
    const float4 bv = *(const float4*)&b[cg];

    for (int t = 0; t < 2; ++t) {
        const size_t row0 = (size_t)blockIdx.x*128 + (size_t)t*64;
        __syncthreads();
        for (int i = tid*4; i < 64*128; i += 1024)
            *(float4*)&xl[i] = *(const float4*)&x[row0*128 + i];
        __syncthreads();

        float acc[16][4];
        #pragma unroll
        for (int r = 0; r < 16; ++r) { acc[r][0]=bv.x; acc[r][1]=bv.y; acc[r][2]=bv.z; acc[r][3]=bv.w; }

        for (int k4 = 0; k4 < 32; ++k4) {
            float4 w0 = *(const float4*)&W[(k4*4+0)*256 + cg];
            float4 w1 = *(const float4*)&W[(k4*4+1)*256 + cg];
            float4 w2 = *(const float4*)&W[(k4*4+2)*256 + cg];
            float4 w3 = *(const float4*)&W[(k4*4+3)*256 + cg];
            #pragma unroll
            for (int r = 0; r < 16; ++r) {
                float4 xv = *(float4*)&xl[(rq*16+r)*128 + k4*4];
                acc[r][0] = fmaf(xv.w,w3.x, fmaf(xv.z,w2.x, fmaf(xv.y,w1.x, fmaf(xv.x,w0.x, acc[r][0]))));
                acc[r][1] = fmaf(xv.w,w3.y, fmaf(xv.z,w2.y, fmaf(xv.y,w1.y, fmaf(xv.x,w0.y, acc[r][1]))));
                acc[r][2] = fmaf(xv.w,w3.z, fmaf(xv.z,w2.z, fmaf(xv.y,w1.z, fmaf(xv.x,w0.z, acc[r][2]))));
                acc[r][3] = fmaf(xv.w,w3.w, fmaf(xv.z,w2.w, fmaf(xv.y,w1.w, fmaf(xv.x,w0.w, acc[r][3]))));
            }
        }
        #pragma unroll
        for (int r = 0; r < 16; ++r) {
            s0 += acc[r][0]; q0 = fmaf(acc[r][0],acc[r][0],q0);
            s1 += acc[r][1]; q1 = fmaf(acc[r][1],acc[r][1],q1);
            s2v+= acc[r][2]; q2 = fmaf(acc[r][2],acc[r][2],q2);
            s3 += acc[r][3]; q3 = fmaf(acc[r][3],acc[r][3],q3);
        }
    }
    __syncthreads();
    float* red = xl;  // reuse
    red[rq*256 + cg+0] = s0; red[rq*256 + cg+1] = s1; red[rq*256 + cg+2] = s2v; red[rq*256 + cg+3] = s3;
    red[1024 + rq*256 + cg+0] = q0; red[1024 + rq*256 + cg+1] = q1;
    red[1024 + rq*256 + cg+2] = q2; red[1024 + rq*256 + cg+3] = q3;
    __syncthreads();
    if (rq == 0) {
        #pragma unroll
        for (int c = 0; c < 4; ++c) {
            int ch = cg + c;
            float ss = red[ch] + red[256+ch] + red[512+ch] + red[768+ch];
            float qq = red[1024+ch] + red[1280+ch] + red[1536+ch] + red[1792+ch];
            psum  [blockIdx.x*256 + ch] = ss;
            psumsq[blockIdx.x*256 + ch] = qq;
        }
    }
}

__global__ void finalize_kernel(const float* __restrict__ psum, const float* __restrict__ psumsq,
                                const float* __restrict__ gamma, const float* __restrict__ beta,
                                float* __restrict__ scale, float* __restrict__ shift) {
    int c = threadIdx.x;
    float s = 0.f, s2 = 0.f;
    for (int bl = 0; bl < 512; ++bl) { s += psum[bl*256+c]; s2 += psumsq[bl*256+c]; }
    float mu  = s  / 65536.0f;
    float var = s2 / 65536.0f - mu*mu;
    float inv = rsqrtf(var + 1e-5f);
    float sc = gamma[c] * inv;
    scale[c] = sc;
    shift[c] = beta[c] - mu * sc;
}

// ---------------- gather + recompute h rows + pooled BN/ReLU ----------------
__global__ __launch_bounds__(256) void out_kernel(const float* __restrict__ x,
                                                  const float* __restrict__ W,
                                                  const float* __restrict__ b,
                                                  const int* __restrict__ nbr,
                                                  const float* __restrict__ scale,
                                                  const float* __restrict__ shift,
                                                  float* __restrict__ out) {
    __shared__ float xl[16*128];   // 8 KiB
    __shared__ int nb[16];
    const int tid = threadIdx.x;
    const int m = blockIdx.x;
    if (tid < 16) nb[tid] = nbr[m*16 + tid];
    __syncthreads();
    for (int i = tid; i < 16*128; i += 256) {
        int r = i >> 7, k = i & 127;
        xl[i] = x[(size_t)nb[r]*128 + k];
    }
    __syncthreads();

    float acc[16];
    const float bias = b[tid];
    #pragma unroll
    for (int r = 0; r < 16; ++r) acc[r] = bias;

    for (int k4 = 0; k4 < 32; ++k4) {
        float w0 = W[(k4*4+0)*256 + tid];
        float w1 = W[(k4*4+1)*256 + tid];
        float w2 = W[(k4*4+2)*256 + tid];
        float w3 = W[(k4*4+3)*256 + tid];
        #pragma unroll
        for (int r = 0; r < 16; ++r) {
            float4 xv = *(float4*)&xl[r*128 + k4*4];
            acc[r] = fmaf(xv.w,w3, fmaf(xv.z,w2, fmaf(xv.y,w1, fmaf(xv.x,w0, acc[r]))));
        }
    }
    const float sc = scale[tid], sh = shift[tid];
    float v = acc[0];
    #pragma unroll
    for (int r = 1; r < 16; ++r) v = (sc >= 0.f) ? fmaxf(v, acc[r]) : fminf(v, acc[r]);
    out[(size_t)m*256 + tid] = fmaxf(fmaf(sc, v, sh), 0.f);
}

// ---------------- launch ----------------
extern "C" void kernel_launch(void* const* d_in, const int* in_sizes, int n_in,
                              void* d_out, int out_size, void* d_ws, size_t ws_size,
                              hipStream_t stream) {
    const float* x     = (const float*)d_in[0];
    const float* pos   = (const float*)d_in[1];
    const int*   batch = (const int*)  d_in[2];
    const float* W     = (const float*)d_in[3];
    const float* b     = (const float*)d_in[4];
    const float* gamma = (const float*)d_in[5];
    const float* beta  = (const float*)d_in[6];

    float* out      = (float*)d_out;
    float* sub_pos  = out + (size_t)MCLUS*C_OUT;
    int*   sub_batch= (int*)(out + (size_t)MCLUS*C_OUT + (size_t)MCLUS*3);

    char* ws = (char*)d_ws;
    int* id                     = (int*)(ws + WS_ID);
    unsigned long long* slots   = (unsigned long long*)(ws + WS_SLOTS);
    int* nbr                    = (int*)(ws + WS_NBR);
    float* psum                 = (float*)(ws + WS_PSUM);
    float* psumsq               = (float*)(ws + WS_PSUMSQ);
    float* scalep               = (float*)(ws + WS_SCALE);
    float* shiftp               = (float*)(ws + WS_SHIFT);

    init_kernel<<<1, 1024, 0, stream>>>(id, slots);
    fps_kernel<<<64, 64, 0, stream>>>(pos, id, slots);
    subout_kernel<<<16, 256, 0, stream>>>(pos, batch, id, sub_pos, sub_batch);
    knn_kernel<<<MCLUS, 64, 0, stream>>>(pos, id, nbr);
    stats_kernel<<<512, 256, 0, stream>>>(x, W, b, psum, psumsq);
    finalize_kernel<<<1, 256, 0, stream>>>(psum, psumsq, gamma, beta, scalep, shiftp);
    out_kernel<<<MCLUS, 256, 0, stream>>>(x, W, b, nbr, scalep, shiftp, out);
}

// Round 4
// 7569.483 us; speedup vs baseline: 2.4534x; 1.2178x over previous
//
#include <hip/hip_runtime.h>
#include <hip/hip_bf16.h>

#define N_PTS 65536
#define MCLUS 4096
#define KNN   16
#define C_IN  128
#define C_OUT 256

typedef unsigned long long u64;
typedef unsigned u32;

// ---------------- workspace layout (bytes) ----------------
// 0        : id[4096]                 int32
// 16384    : slots[2][64][32]         u64   (mailbox: parity x block x word, 256B/block)
// 49152    : nbr[4096*16]             int32
// 311296   : psum [512*256]           f32
// 835584   : psumsq[512*256]          f32
// 1359872  : scale[256]               f32
// 1360896  : shift[256]               f32
#define WS_ID     0
#define WS_SLOTS  16384
#define WS_NBR    49152
#define WS_PSUM   311296
#define WS_PSUMSQ 835584
#define WS_SCALE  1359872
#define WS_SHIFT  1360896

// ---------------- init: reset sync mailbox + id[0] ----------------
__global__ void init_kernel(int* __restrict__ id, u64* __restrict__ slots) {
    int t = threadIdx.x;
    for (int i = t; i < 4096; i += 1024) slots[i] = 0ull;  // tag 0 never used (tags start at 1)
    if (t == 0) id[0] = 0;
}

// exact reference arithmetic: ((dx*dx + dy*dy) + dz*dz), no FMA
__device__ __forceinline__ float dist3(float ax, float ay, float az,
                                       float bx, float by, float bz) {
    float dx = __fsub_rn(ax, bx), dy = __fsub_rn(ay, by), dz = __fsub_rn(az, bz);
    return __fadd_rn(__fadd_rn(__fmul_rn(dx, dx), __fmul_rn(dy, dy)), __fmul_rn(dz, dz));
}

__device__ __forceinline__ u32 wave_max_u32(u32 v) {
    #pragma unroll
    for (int off = 32; off > 0; off >>= 1) {
        u32 o = __shfl_xor(v, off);
        v = o > v ? o : v;
    }
    return v;
}

// argmax over 48-bit keys (md32<<16 | inv16); returns winning lane.
// 32-bit butterfly fast path; exact tie resolution via aux (inv16, globally unique idx).
__device__ __forceinline__ int wave_argmax48(u64 k48) {
    u32 hi = (u32)(k48 >> 16);
    u32 him = wave_max_u32(hi);
    u64 ball = __ballot(hi == him);
    if (__popcll(ball) > 1) {
        u32 a = (hi == him) ? (u32)(k48 & 0xFFFFull) : 0u;
        u32 am = wave_max_u32(a);
        ball = __ballot((hi == him) && (a == am));
    }
    return __ffsll((long long)ball) - 1;
}

// ---------------- FPS: batched-8 optimistic simulation + exact verify ----------
// 64 blocks x 64 threads (1 wave), 16 points/thread, all state in VGPRs.
// Steady state: ONE cross-XCD mailbox round per 8 FPS steps.
// Mailbox words are self-tagged (low 16 bits = round+1), relaxed agent-scope atomics,
// double-buffered by round parity (block skew provably <=1 round).
__global__ __launch_bounds__(64) void fps_kernel(const float* __restrict__ pos,
                                                 int* __restrict__ id,
                                                 u64* __restrict__ slots) {
    const int lane = threadIdx.x;
    const int blk  = blockIdx.x;
    __shared__ float bku[1024];    // md snapshot for rollback (4 KiB)

    float px[16], py[16], pz[16], md[16];
    const float c0x = pos[0], c0y = pos[1], c0z = pos[2];
    #pragma unroll
    for (int e = 0; e < 16; ++e) {
        int gi = blk * 1024 + e * 64 + lane;
        px[e] = pos[gi * 3 + 0]; py[e] = pos[gi * 3 + 1]; pz[e] = pos[gi * 3 + 2];
        md[e] = dist3(px[e], py[e], pz[e], c0x, c0y, c0z);   // invariant: md through c_0
    }

    int r = 0;              // mailbox round counter (tag = r+1)
    bool pending = false;   // my violation flag for the previous batch

    // exact single-step protocol (round-3 scheme): select on current md, publish,
    // poll, apply winner. Used for violation replay and the final 7 steps.
    auto slow_round = [&](int rr, int s) {
        u64 bk = 0; float bx = 0.f, by = 0.f, bz = 0.f;
        #pragma unroll
        for (int e = 0; e < 16; ++e) {
            u32 inv = 0xFFFFu - (u32)(blk * 1024 + e * 64 + lane);
            u64 k = ((u64)__float_as_uint(md[e]) << 16) | inv;
            bool bt = k > bk;
            bk = bt ? k : bk; bx = bt ? px[e] : bx; by = bt ? py[e] : by; bz = bt ? pz[e] : bz;
        }
        int src = wave_argmax48(bk);
        float wx = __shfl(bx, src), wy = __shfl(by, src), wz = __shfl(bz, src);
        u64 kb = __shfl(bk, src);

        const u64 tg = (u64)((rr + 1) & 0xFFFF);
        u64* base = &slots[(u32)(rr & 1) * 2048];
        {
            u64 w0 = (kb << 16) | tg;
            u64 w1 = ((u64)__float_as_uint(wx) << 32) | tg;
            u64 w2 = ((u64)__float_as_uint(wy) << 32) | tg;
            u64 w3 = ((u64)__float_as_uint(wz) << 32) | tg;
            u64 wv = (lane == 0) ? w0 : (lane == 1) ? w1 : (lane == 2) ? w2 : w3;
            if (lane < 4)
                __hip_atomic_store(&base[(u32)blk * 32 + (u32)lane], wv,
                                   __ATOMIC_RELAXED, __HIP_MEMORY_SCOPE_AGENT);
        }
        u64* bp = &base[(u32)lane * 32];
        u64 v0, v1, v2, v3;
        for (;;) {
            v0 = __hip_atomic_load(&bp[0], __ATOMIC_RELAXED, __HIP_MEMORY_SCOPE_AGENT);
            v1 = __hip_atomic_load(&bp[1], __ATOMIC_RELAXED, __HIP_MEMORY_SCOPE_AGENT);
            v2 = __hip_atomic_load(&bp[2], __ATOMIC_RELAXED, __HIP_MEMORY_SCOPE_AGENT);
            v3 = __hip_atomic_load(&bp[3], __ATOMIC_RELAXED, __HIP_MEMORY_SCOPE_AGENT);
            u64 bad = ((v0 ^ tg) | (v1 ^ tg) | (v2 ^ tg) | (v3 ^ tg)) & 0xFFFFull;
            if (bad == 0ull) break;
        }
        u64 k2 = v0 >> 16;
        int s2 = wave_argmax48(k2);
        u64 kw = __shfl(k2, s2);
        float cx = __shfl(__uint_as_float((u32)(v1 >> 32)), s2);
        float cy = __shfl(__uint_as_float((u32)(v2 >> 32)), s2);
        float cz = __shfl(__uint_as_float((u32)(v3 >> 32)), s2);
        if (blk == 0 && lane == 0) id[s] = (int)(0xFFFFu - (u32)(kw & 0xFFFFull));
        #pragma unroll
        for (int e = 0; e < 16; ++e)
            md[e] = fminf(md[e], dist3(px[e], py[e], pz[e], cx, cy, cz));
    };

    // batches 0..510 = steps 1..4088; B==511 is the confirm-only round for batch 510
    for (int B = 0; B <= 511; ++B) {
        // ---- extract 8 candidates: max of each 8-lane segment (disjoint 128-pt groups) ----
        u64 bk = 0; float bx = 0.f, by = 0.f, bz = 0.f;
        #pragma unroll
        for (int e = 0; e < 16; ++e) {
            u32 inv = 0xFFFFu - (u32)(blk * 1024 + e * 64 + lane);
            u64 k = ((u64)__float_as_uint(md[e]) << 16) | inv;
            bool bt = k > bk;
            bk = bt ? k : bk; bx = bt ? px[e] : bx; by = bt ? py[e] : by; bz = bt ? pz[e] : bz;
        }
        u64 ks = bk;
        #pragma unroll
        for (int off = 1; off <= 4; off <<= 1) {
            u64 o = __shfl_xor(ks, off);
            if (o > ks) ks = o;
        }
        {   // gather segment-winner position (key is unique: contains idx)
            u64 ball = __ballot(bk == ks);
            int segbase = (lane >> 3) << 3;
            int ssrc = __ffsll((long long)(ball & (0xFFull << segbase))) - 1;
            bx = __shfl(bx, ssrc); by = __shfl(by, ssrc); bz = __shfl(bz, ssrc);
        }

        // ---- publish 25 self-tagged words (24 = 8 cands x 3, 1 flag) ----
        const u64 tg = (u64)((r + 1) & 0xFFFF);
        u64* base = &slots[(u32)(r & 1) * 2048];
        {
            int c = lane / 3; if (c > 7) c = 7;
            int p = lane - c * 3;
            int srcl = 8 * c;
            u64 kk  = __shfl(ks, srcl);
            float gx = __shfl(bx, srcl), gy = __shfl(by, srcl), gz = __shfl(bz, srcl);
            u32 hi, mid;
            if (p == 0)      { hi = __float_as_uint(gx); mid = (u32)(kk & 0xFFFFull); }
            else if (p == 1) { hi = __float_as_uint(gy); mid = (u32)(kk >> 32) & 0xFFFFu; }
            else             { hi = __float_as_uint(gz); mid = (u32)(kk >> 16) & 0xFFFFu; }
            u64 wd = ((u64)hi << 32) | ((u64)mid << 16) | tg;
            if (lane == 24) wd = ((u64)(pending ? 1u : 0u) << 16) | tg;
            if (lane < 25)
                __hip_atomic_store(&base[(u32)blk * 32 + (u32)lane], wd,
                                   __ATOMIC_RELAXED, __HIP_MEMORY_SCOPE_AGENT);
        }

        // ---- poll: lane l waits for block l's 25 words (reload only stale) ----
        u64 w[25]; u32 valid = 0;
        {
            u64* bp = &base[(u32)lane * 32];
            do {
                #pragma unroll
                for (int i = 0; i < 25; ++i)
                    if (!(valid & (1u << i)))
                        w[i] = __hip_atomic_load(&bp[i], __ATOMIC_RELAXED, __HIP_MEMORY_SCOPE_AGENT);
                #pragma unroll
                for (int i = 0; i < 25; ++i)
                    if ((u32)(w[i] & 0xFFFFull) == (u32)tg) valid |= (1u << i);
            } while (valid != 0x1FFFFFFu);
        }
        ++r;

        bool anyviol = (__ballot(((w[24] >> 16) & 1ull) != 0ull) != 0ull);
        if (anyviol) {
            // rollback to pre-batch-(B-1) state and replay batch B-1 exactly
            #pragma unroll
            for (int e = 0; e < 16; ++e) md[e] = bku[e * 64 + lane];
            int sbase = 8 * (B - 1) + 1;
            for (int sub = 0; sub < 8; ++sub) { slow_round(r, sbase + sub); ++r; }
            pending = false;
            --B; continue;   // retry this exchange
        }
        if (B == 511) break; // batch 510 confirmed clean

        // ---- parse candidates (lane l holds block l's 8) ----
        float cpx[8], cpy[8], cpz[8], cmdf[8]; u32 cinv[8];
        #pragma unroll
        for (int c = 0; c < 8; ++c) {
            u64 a = w[3 * c], b = w[3 * c + 1], d = w[3 * c + 2];
            cpx[c] = __uint_as_float((u32)(a >> 32));
            cpy[c] = __uint_as_float((u32)(b >> 32));
            cpz[c] = __uint_as_float((u32)(d >> 32));
            cinv[c] = (u32)(a >> 16) & 0xFFFFu;
            u32 mdb = (((u32)(b >> 16) & 0xFFFFu) << 16) | ((u32)(d >> 16) & 0xFFFFu);
            cmdf[c] = __uint_as_float(mdb);
        }

        // ---- simulate 8 substeps over the 512-candidate union (identical in all blocks) ----
        u64 wk48[8]; float wxa[8], wya[8], wza[8];
        float pwx = 0.f, pwy = 0.f, pwz = 0.f;
        #pragma unroll
        for (int j = 0; j < 8; ++j) {
            if (j) {
                #pragma unroll
                for (int c = 0; c < 8; ++c)
                    cmdf[c] = fminf(cmdf[c], dist3(cpx[c], cpy[c], cpz[c], pwx, pwy, pwz));
            }
            u64 bk2 = 0; float b2x = 0.f, b2y = 0.f, b2z = 0.f;
            #pragma unroll
            for (int c = 0; c < 8; ++c) {
                u64 k = ((u64)__float_as_uint(cmdf[c]) << 16) | cinv[c];
                bool bt = k > bk2;
                bk2 = bt ? k : bk2; b2x = bt ? cpx[c] : b2x; b2y = bt ? cpy[c] : b2y; b2z = bt ? cpz[c] : b2z;
            }
            int src = wave_argmax48(bk2);
            u64 kw = __shfl(bk2, src);
            float wx = __shfl(b2x, src), wy = __shfl(b2y, src), wz = __shfl(b2z, src);
            wk48[j] = kw; wxa[j] = wx; wya[j] = wy; wza[j] = wz;
            pwx = wx; pwy = wy; pwz = wz;
            if (blk == 0 && lane == 0) id[8 * B + 1 + j] = (int)(0xFFFFu - (u32)(kw & 0xFFFFull));
        }

        // ---- snapshot, then verify + apply (exactness check incl. tie-break) ----
        #pragma unroll
        for (int e = 0; e < 16; ++e) bku[e * 64 + lane] = md[e];
        bool viol = false;
        #pragma unroll
        for (int j = 0; j < 8; ++j) {
            #pragma unroll
            for (int e = 0; e < 16; ++e) {
                u32 inv = 0xFFFFu - (u32)(blk * 1024 + e * 64 + lane);
                u64 vk = ((u64)__float_as_uint(md[e]) << 16) | inv;
                viol |= (vk > wk48[j]);
            }
            #pragma unroll
            for (int e = 0; e < 16; ++e)
                md[e] = fminf(md[e], dist3(px[e], py[e], pz[e], wxa[j], wya[j], wza[j]));
        }
        pending = (__ballot(viol) != 0ull);
    }

    // final 7 steps: 4089..4095
    for (int s = 4089; s < 4096; ++s) { slow_round(r, s); ++r; }
}

// ---------------- sub_pos / sub_batch outputs ----------------
__global__ void subout_kernel(const float* __restrict__ pos, const int* __restrict__ batch,
                              const int* __restrict__ id, float* __restrict__ sub_pos,
                              int* __restrict__ sub_batch) {
    int m = blockIdx.x * blockDim.x + threadIdx.x;
    if (m >= MCLUS) return;
    int idx = id[m];
    sub_pos[m*3+0] = pos[idx*3+0];
    sub_pos[m*3+1] = pos[idx*3+1];
    sub_pos[m*3+2] = pos[idx*3+2];
    sub_batch[m] = batch[idx];
}

// ---------------- kNN: one wave per query ----------------
// d2 = (|q|^2 - 2*q.p) + |p|^2, all ops correctly-rounded, no FMA (match reference bits).
__global__ __launch_bounds__(64) void knn_kernel(const float* __restrict__ pos,
                                                 const int* __restrict__ id,
                                                 int* __restrict__ nbr) {
    const int q = blockIdx.x;
    const int lane = threadIdx.x;
    const int qi = id[q];
    const float qx = pos[qi*3+0], qy = pos[qi*3+1], qz = pos[qi*3+2];
    const float nq = __fadd_rn(__fadd_rn(__fmul_rn(qx,qx), __fmul_rn(qy,qy)), __fmul_rn(qz,qz));

    float dl[KNN]; int il[KNN];
    #pragma unroll
    for (int t = 0; t < KNN; ++t) { dl[t] = __builtin_inff(); il[t] = 0x7FFFFFFF; }

    for (int j = lane; j < N_PTS; j += 64) {
        float px = pos[j*3+0], py = pos[j*3+1], pz = pos[j*3+2];
        float npj = __fadd_rn(__fadd_rn(__fmul_rn(px,px), __fmul_rn(py,py)), __fmul_rn(pz,pz));
        float dot = __fadd_rn(__fadd_rn(__fmul_rn(qx,px), __fmul_rn(qy,py)), __fmul_rn(qz,pz));
        float d2  = __fadd_rn(__fsub_rn(nq, __fmul_rn(2.0f, dot)), npj);
        if (d2 < dl[KNN-1] || (d2 == dl[KNN-1] && j < il[KNN-1])) {
            dl[KNN-1] = d2; il[KNN-1] = j;
            #pragma unroll
            for (int t = KNN-1; t > 0; --t) {
                float a = dl[t-1], bq = dl[t];
                int   ai = il[t-1], bi = il[t];
                bool sw = (bq < a) || (bq == a && bi < ai);
                dl[t-1] = sw ? bq : a;  dl[t] = sw ? a : bq;
                il[t-1] = sw ? bi : ai; il[t] = sw ? ai : bi;
            }
        }
    }

    __shared__ float sd[64][KNN];
    __shared__ int   si[64][KNN];
    #pragma unroll
    for (int t = 0; t < KNN; ++t) { sd[lane][t] = dl[t]; si[lane][t] = il[t]; }
    __syncthreads();

    // 64-way merge of sorted lists: 16 rounds of wave-min over heads
    int ptr = 0;
    for (int rr = 0; rr < KNN; ++rr) {
        unsigned long long key = ~0ull;
        if (ptr < KNN) {
            unsigned u = __float_as_uint(sd[lane][ptr]);
            unsigned mu = (u >> 31) ? ~u : (u | 0x80000000u);   // order-preserving
            key = ((unsigned long long)mu << 32) | (unsigned)si[lane][ptr];
        }
        unsigned long long m = key;
        #pragma unroll
        for (int off = 32; off > 0; off >>= 1) {
            unsigned long long o = __shfl_xor(m, off);
            if (o < m) m = o;
        }
        if (key == m) ptr++;
        if (lane == 0) nbr[q*KNN + rr] = (int)(m & 0xFFFFFFFFull);
    }
}

// ---------------- BN stats: h = x@W + b, per-channel sum & sumsq ----------------
__global__ __launch_bounds__(256) void stats_kernel(const float* __restrict__ x,
                                                    const float* __restrict__ W,
                                                    const float* __restrict__ b,
                                                    float* __restrict__ psum,
                                                    float* __restrict__ psumsq) {
    __shared__ float xl[64*128];     // 32 KiB
    const int tid = threadIdx.x;
    const int cg = (tid & 63) * 4;   // channel group base
    const int rq = tid >> 6;         // row quarter (0..3)
    float s0=0,s1=0,s2v=0,s3=0, q0=0,q1=0,q2=0,q3=0;
    const float4 bv = *(const float4*)&b[cg];

    for (int t = 0; t < 2; ++t) {
        const size_t row0 = (size_t)blockIdx.x*128 + (size_t)t*64;
        __syncthreads();
        for (int i = tid*4; i < 64*128; i += 1024)
            *(float4*)&xl[i] = *(const float4*)&x[row0*128 + i];
        __syncthreads();

        float acc[16][4];
        #pragma unroll
        for (int rr = 0; rr < 16; ++rr) { acc[rr][0]=bv.x; acc[rr][1]=bv.y; acc[rr][2]=bv.z; acc[rr][3]=bv.w; }

        for (int k4 = 0; k4 < 32; ++k4) {
            float4 w0 = *(const float4*)&W[(k4*4+0)*256 + cg];
            float4 w1 = *(const float4*)&W[(k4*4+1)*256 + cg];
            float4 w2 = *(const float4*)&W[(k4*4+2)*256 + cg];
            float4 w3 = *(const float4*)&W[(k4*4+3)*256 + cg];
            #pragma unroll
            for (int rr = 0; rr < 16; ++rr) {
                float4 xv = *(float4*)&xl[(rq*16+rr)*128 + k4*4];
                acc[rr][0] = fmaf(xv.w,w3.x, fmaf(xv.z,w2.x, fmaf(xv.y,w1.x, fmaf(xv.x,w0.x, acc[rr][0]))));
                acc[rr][1] = fmaf(xv.w,w3.y, fmaf(xv.z,w2.y, fmaf(xv.y,w1.y, fmaf(xv.x,w0.y, acc[rr][1]))));
                acc[rr][2] = fmaf(xv.w,w3.z, fmaf(xv.z,w2.z, fmaf(xv.y,w1.z, fmaf(xv.x,w0.z, acc[rr][2]))));
                acc[rr][3] = fmaf(xv.w,w3.w, fmaf(xv.z,w2.w, fmaf(xv.y,w1.w, fmaf(xv.x,w0.w, acc[rr][3]))));
            }
        }
        #pragma unroll
        for (int rr = 0; rr < 16; ++rr) {
            s0 += acc[rr][0]; q0 = fmaf(acc[rr][0],acc[rr][0],q0);
            s1 += acc[rr][1]; q1 = fmaf(acc[rr][1],acc[rr][1],q1);
            s2v+= acc[rr][2]; q2 = fmaf(acc[rr][2],acc[rr][2],q2);
            s3 += acc[rr][3]; q3 = fmaf(acc[rr][3],acc[rr][3],q3);
        }
    }
    __syncthreads();
    float* red = xl;  // reuse
    red[rq*256 + cg+0] = s0; red[rq*256 + cg+1] = s1; red[rq*256 + cg+2] = s2v; red[rq*256 + cg+3] = s3;
    red[1024 + rq*256 + cg+0] = q0; red[1024 + rq*256 + cg+1] = q1;
    red[1024 + rq*256 + cg+2] = q2; red[1024 + rq*256 + cg+3] = q3;
    __syncthreads();
    if (rq == 0) {
        #pragma unroll
        for (int c = 0; c < 4; ++c) {
            int ch = cg + c;
            float ss = red[ch] + red[256+ch] + red[512+ch] + red[768+ch];
            float qq = red[1024+ch] + red[1280+ch] + red[1536+ch] + red[1792+ch];
            psum  [blockIdx.x*256 + ch] = ss;
            psumsq[blockIdx.x*256 + ch] = qq;
        }
    }
}

__global__ void finalize_kernel(const float* __restrict__ psum, const float* __restrict__ psumsq,
                                const float* __restrict__ gamma, const float* __restrict__ beta,
                                float* __restrict__ scale, float* __restrict__ shift) {
    int c = threadIdx.x;
    float s = 0.f, s2 = 0.f;
    for (int bl = 0; bl < 512; ++bl) { s += psum[bl*256+c]; s2 += psumsq[bl*256+c]; }
    float mu  = s  / 65536.0f;
    float var = s2 / 65536.0f - mu*mu;
    float inv = rsqrtf(var + 1e-5f);
    float sc = gamma[c] * inv;
    scale[c] = sc;
    shift[c] = beta[c] - mu * sc;
}

// ---------------- gather + recompute h rows + pooled BN/ReLU ----------------
__global__ __launch_bounds__(256) void out_kernel(const float* __restrict__ x,
                                                  const float* __restrict__ W,
                                                  const float* __restrict__ b,
                                                  const int* __restrict__ nbr,
                                                  const float* __restrict__ scale,
                                                  const float* __restrict__ shift,
                                                  float* __restrict__ out) {
    __shared__ float xl[16*128];   // 8 KiB
    __shared__ int nb[16];
    const int tid = threadIdx.x;
    const int m = blockIdx.x;
    if (tid < 16) nb[tid] = nbr[m*16 + tid];
    __syncthreads();
    for (int i = tid; i < 16*128; i += 256) {
        int rr = i >> 7, k = i & 127;
        xl[i] = x[(size_t)nb[rr]*128 + k];
    }
    __syncthreads();

    float acc[16];
    const float bias = b[tid];
    #pragma unroll
    for (int rr = 0; rr < 16; ++rr) acc[rr] = bias;

    for (int k4 = 0; k4 < 32; ++k4) {
        float w0 = W[(k4*4+0)*256 + tid];
        float w1 = W[(k4*4+1)*256 + tid];
        float w2 = W[(k4*4+2)*256 + tid];
        float w3 = W[(k4*4+3)*256 + tid];
        #pragma unroll
        for (int rr = 0; rr < 16; ++rr) {
            float4 xv = *(float4*)&xl[rr*128 + k4*4];
            acc[rr] = fmaf(xv.w,w3, fmaf(xv.z,w2, fmaf(xv.y,w1, fmaf(xv.x,w0, acc[rr]))));
        }
    }
    const float sc = scale[tid], sh = shift[tid];
    float v = acc[0];
    #pragma unroll
    for (int rr = 1; rr < 16; ++rr) v = (sc >= 0.f) ? fmaxf(v, acc[rr]) : fminf(v, acc[rr]);
    out[(size_t)m*256 + tid] = fmaxf(fmaf(sc, v, sh), 0.f);
}

// ---------------- launch ----------------
extern "C" void kernel_launch(void* const* d_in, const int* in_sizes, int n_in,
                              void* d_out, int out_size, void* d_ws, size_t ws_size,
                              hipStream_t stream) {
    const float* x     = (const float*)d_in[0];
    const float* pos   = (const float*)d_in[1];
    const int*   batch = (const int*)  d_in[2];
    const float* W     = (const float*)d_in[3];
    const float* b     = (const float*)d_in[4];
    const float* gamma = (const float*)d_in[5];
    const float* beta  = (const float*)d_in[6];

    float* out      = (float*)d_out;
    float* sub_pos  = out + (size_t)MCLUS*C_OUT;
    int*   sub_batch= (int*)(out + (size_t)MCLUS*C_OUT + (size_t)MCLUS*3);

    char* ws = (char*)d_ws;
    int* id        = (int*)(ws + WS_ID);
    u64* slots     = (u64*)(ws + WS_SLOTS);
    int* nbr       = (int*)(ws + WS_NBR);
    float* psum    = (float*)(ws + WS_PSUM);
    float* psumsq  = (float*)(ws + WS_PSUMSQ);
    float* scalep  = (float*)(ws + WS_SCALE);
    float* shiftp  = (float*)(ws + WS_SHIFT);

    init_kernel<<<1, 1024, 0, stream>>>(id, slots);
    fps_kernel<<<64, 64, 0, stream>>>(pos, id, slots);
    subout_kernel<<<16, 256, 0, stream>>>(pos, batch, id, sub_pos, sub_batch);
    knn_kernel<<<MCLUS, 64, 0, stream>>>(pos, id, nbr);
    stats_kernel<<<512, 256, 0, stream>>>(x, W, b, psum, psumsq);
    finalize_kernel<<<1, 256, 0, stream>>>(psum, psumsq, gamma, beta, scalep, shiftp);
    out_kernel<<<MCLUS, 256, 0, stream>>>(x, W, b, nbr, scalep, shiftp, out);
}

// Round 5
// 7235.251 us; speedup vs baseline: 2.5667x; 1.0462x over previous
//
#include <hip/hip_runtime.h>
#include <hip/hip_bf16.h>

#define N_PTS 65536
#define MCLUS 4096
#define KNN   16
#define C_IN  128
#define C_OUT 256

typedef unsigned long long u64;
typedef unsigned u32;

// ---------------- workspace layout (bytes) ----------------
#define WS_ID     0
#define WS_SLOTS  16384
#define WS_NBR    49152
#define WS_PSUM   311296
#define WS_PSUMSQ 835584
#define WS_SCALE  1359872
#define WS_SHIFT  1360896

// ---------------- init: reset sync mailbox + id[0] ----------------
__global__ void init_kernel(int* __restrict__ id, u64* __restrict__ slots) {
    int t = threadIdx.x;
    for (int i = t; i < 4096; i += 1024) slots[i] = 0ull;  // tag 0 never used (tags start at 1)
    if (t == 0) id[0] = 0;
}

// exact reference arithmetic: ((dx*dx + dy*dy) + dz*dz), no FMA
__device__ __forceinline__ float dist3(float ax, float ay, float az,
                                       float bx, float by, float bz) {
    float dx = __fsub_rn(ax, bx), dy = __fsub_rn(ay, by), dz = __fsub_rn(az, bz);
    return __fadd_rn(__fadd_rn(__fmul_rn(dx, dx), __fmul_rn(dy, dy)), __fmul_rn(dz, dz));
}

__device__ __forceinline__ u32 wave_max_u32(u32 v) {
    #pragma unroll
    for (int off = 32; off > 0; off >>= 1) {
        u32 o = __shfl_xor(v, off);
        v = o > v ? o : v;
    }
    return v;
}

// argmax over 48-bit keys (md32<<16 | inv16); returns winning lane.
__device__ __forceinline__ int wave_argmax48(u64 k48) {
    u32 hi = (u32)(k48 >> 16);
    u32 him = wave_max_u32(hi);
    u64 ball = __ballot(hi == him);
    if (__popcll(ball) > 1) {
        u32 a = (hi == him) ? (u32)(k48 & 0xFFFFull) : 0u;
        u32 am = wave_max_u32(a);
        ball = __ballot((hi == him) && (a == am));
    }
    return __ffsll((long long)ball) - 1;
}

// order-preserving float->u32 (handles negatives)
__device__ __forceinline__ u32 fkey(float v) {
    u32 u = __float_as_uint(v);
    return (u >> 31) ? ~u : (u | 0x80000000u);
}

// segmented bitonic sort: ascending sort of each segsize-chunk of arr[0..1024).
// single wave (64 lanes); keys unique (low bits carry index).
__device__ __forceinline__ void bsort_seg(u64* arr, int segsize, int lane) {
    const int half = segsize >> 1;
    for (int k = 2; k <= segsize; k <<= 1) {
        for (int j = k >> 1; j > 0; j >>= 1) {
            for (int t = lane; t < 512; t += 64) {
                int seg = t / half;
                int tt  = t - seg * half;
                int io  = ((tt & ~(j - 1)) << 1) | (tt & (j - 1));  // local idx, j-bit clear
                int i   = seg * segsize + io;
                int l   = i | j;
                u64 a = arr[i], b = arr[l];
                bool up = ((io & k) == 0);
                if ((a > b) == up) { arr[i] = b; arr[l] = a; }
            }
            __syncthreads();
        }
    }
}

// ---------------- FPS: batched-8 optimistic simulation + exact verify ----------
// 64 blocks x 64 threads (1 wave), 16 points/thread, all state in VGPRs.
// NEW: one-time within-block KD-style spatial sort -> segments are tight boxes,
// making the published per-segment champions robust across 8 simulated substeps.
// Steady state: ONE cross-XCD mailbox round per 8 FPS steps.
__global__ __launch_bounds__(64) void fps_kernel(const float* __restrict__ pos,
                                                 int* __restrict__ id,
                                                 u64* __restrict__ slots) {
    const int lane = threadIdx.x;
    const int blk  = blockIdx.x;
    __shared__ float sx[1024], sy[1024], sz[1024];   // 12 KiB coords (orig local order)
    __shared__ u64  arr[1024];                       // 8 KiB sort keys/payload
    __shared__ float bku[1024];                      // 4 KiB md snapshot for rollback

    // ---- load coords to LDS, build x-keys ----
    for (int p = lane; p < 1024; p += 64) {
        int gi = blk * 1024 + p;
        sx[p] = pos[gi * 3 + 0]; sy[p] = pos[gi * 3 + 1]; sz[p] = pos[gi * 3 + 2];
    }
    __syncthreads();
    for (int p = lane; p < 1024; p += 64)
        arr[p] = ((u64)fkey(sx[p]) << 32) | (u32)p;
    __syncthreads();
    bsort_seg(arr, 1024, lane);                      // split x -> 2 x 512
    for (int p = lane; p < 1024; p += 64) {
        u32 li = (u32)(arr[p] & 0xFFFFull);
        arr[p] = ((u64)fkey(sy[li]) << 32) | li;
    }
    __syncthreads();
    bsort_seg(arr, 512, lane);                       // split y -> 4 x 256
    for (int p = lane; p < 1024; p += 64) {
        u32 li = (u32)(arr[p] & 0xFFFFull);
        arr[p] = ((u64)fkey(sz[li]) << 32) | li;
    }
    __syncthreads();
    bsort_seg(arr, 256, lane);                       // split z -> 8 x 128 tight boxes

    // ---- pick up per-thread points: lane-group g=lane>>3 owns sorted[g*128, g*128+128) ----
    float px[16], py[16], pz[16], md[16];
    u32 inv[16];
    const float c0x = pos[0], c0y = pos[1], c0z = pos[2];
    #pragma unroll
    for (int e = 0; e < 16; ++e) {
        int sp = (lane >> 3) * 128 + e * 8 + (lane & 7);
        u32 li = (u32)(arr[sp] & 0xFFFFull);
        px[e] = sx[li]; py[e] = sy[li]; pz[e] = sz[li];
        inv[e] = 0xFFFFu - (u32)(blk * 1024 + (int)li);
        md[e] = dist3(px[e], py[e], pz[e], c0x, c0y, c0z);
    }

    int r = 0;              // mailbox round counter (tag = r+1)
    bool pending = false;   // my violation flag for the previous batch

    // exact single-step protocol (round-3 scheme), for replay and the final 7 steps
    auto slow_round = [&](int rr, int s) {
        u64 bk = 0; float bx = 0.f, by = 0.f, bz = 0.f;
        #pragma unroll
        for (int e = 0; e < 16; ++e) {
            u64 k = ((u64)__float_as_uint(md[e]) << 16) | inv[e];
            bool bt = k > bk;
            bk = bt ? k : bk; bx = bt ? px[e] : bx; by = bt ? py[e] : by; bz = bt ? pz[e] : bz;
        }
        int src = wave_argmax48(bk);
        float wx = __shfl(bx, src), wy = __shfl(by, src), wz = __shfl(bz, src);
        u64 kb = __shfl(bk, src);

        const u64 tg = (u64)((rr + 1) & 0xFFFF);
        u64* base = &slots[(u32)(rr & 1) * 2048];
        {
            u64 w0 = (kb << 16) | tg;
            u64 w1 = ((u64)__float_as_uint(wx) << 32) | tg;
            u64 w2 = ((u64)__float_as_uint(wy) << 32) | tg;
            u64 w3 = ((u64)__float_as_uint(wz) << 32) | tg;
            u64 wv = (lane == 0) ? w0 : (lane == 1) ? w1 : (lane == 2) ? w2 : w3;
            if (lane < 4)
                __hip_atomic_store(&base[(u32)blk * 32 + (u32)lane], wv,
                                   __ATOMIC_RELAXED, __HIP_MEMORY_SCOPE_AGENT);
        }
        u64* bp = &base[(u32)lane * 32];
        u64 v0, v1, v2, v3;
        for (;;) {
            v0 = __hip_atomic_load(&bp[0], __ATOMIC_RELAXED, __HIP_MEMORY_SCOPE_AGENT);
            v1 = __hip_atomic_load(&bp[1], __ATOMIC_RELAXED, __HIP_MEMORY_SCOPE_AGENT);
            v2 = __hip_atomic_load(&bp[2], __ATOMIC_RELAXED, __HIP_MEMORY_SCOPE_AGENT);
            v3 = __hip_atomic_load(&bp[3], __ATOMIC_RELAXED, __HIP_MEMORY_SCOPE_AGENT);
            u64 bad = ((v0 ^ tg) | (v1 ^ tg) | (v2 ^ tg) | (v3 ^ tg)) & 0xFFFFull;
            if (bad == 0ull) break;
        }
        u64 k2 = v0 >> 16;
        int s2 = wave_argmax48(k2);
        u64 kw = __shfl(k2, s2);
        float cx = __shfl(__uint_as_float((u32)(v1 >> 32)), s2);
        float cy = __shfl(__uint_as_float((u32)(v2 >> 32)), s2);
        float cz = __shfl(__uint_as_float((u32)(v3 >> 32)), s2);
        if (blk == 0 && lane == 0) id[s] = (int)(0xFFFFu - (u32)(kw & 0xFFFFull));
        #pragma unroll
        for (int e = 0; e < 16; ++e)
            md[e] = fminf(md[e], dist3(px[e], py[e], pz[e], cx, cy, cz));
    };

    // batches 0..510 = steps 1..4088; B==511 is the confirm-only round for batch 510
    for (int B = 0; B <= 511; ++B) {
        // ---- extract 8 candidates: max of each 8-lane segment (tight spatial boxes) ----
        u64 bk = 0; float bx = 0.f, by = 0.f, bz = 0.f;
        #pragma unroll
        for (int e = 0; e < 16; ++e) {
            u64 k = ((u64)__float_as_uint(md[e]) << 16) | inv[e];
            bool bt = k > bk;
            bk = bt ? k : bk; bx = bt ? px[e] : bx; by = bt ? py[e] : by; bz = bt ? pz[e] : bz;
        }
        u64 ks = bk;
        #pragma unroll
        for (int off = 1; off <= 4; off <<= 1) {
            u64 o = __shfl_xor(ks, off);
            if (o > ks) ks = o;
        }
        {   // gather segment-winner position (key unique: contains idx)
            u64 ball = __ballot(bk == ks);
            int segbase = (lane >> 3) << 3;
            int ssrc = __ffsll((long long)(ball & (0xFFull << segbase))) - 1;
            bx = __shfl(bx, ssrc); by = __shfl(by, ssrc); bz = __shfl(bz, ssrc);
        }

        // ---- publish 25 self-tagged words (24 = 8 cands x 3, 1 flag) ----
        const u64 tg = (u64)((r + 1) & 0xFFFF);
        u64* base = &slots[(u32)(r & 1) * 2048];
        {
            int c = lane / 3; if (c > 7) c = 7;
            int p = lane - c * 3;
            int srcl = 8 * c;
            u64 kk  = __shfl(ks, srcl);
            float gx = __shfl(bx, srcl), gy = __shfl(by, srcl), gz = __shfl(bz, srcl);
            u32 hi, mid;
            if (p == 0)      { hi = __float_as_uint(gx); mid = (u32)(kk & 0xFFFFull); }
            else if (p == 1) { hi = __float_as_uint(gy); mid = (u32)(kk >> 32) & 0xFFFFu; }
            else             { hi = __float_as_uint(gz); mid = (u32)(kk >> 16) & 0xFFFFu; }
            u64 wd = ((u64)hi << 32) | ((u64)mid << 16) | tg;
            if (lane == 24) wd = ((u64)(pending ? 1u : 0u) << 16) | tg;
            if (lane < 25)
                __hip_atomic_store(&base[(u32)blk * 32 + (u32)lane], wd,
                                   __ATOMIC_RELAXED, __HIP_MEMORY_SCOPE_AGENT);
        }

        // ---- poll: lane l waits for block l's 25 words (reload only stale) ----
        u64 w[25]; u32 valid = 0;
        {
            u64* bp = &base[(u32)lane * 32];
            do {
                #pragma unroll
                for (int i = 0; i < 25; ++i)
                    if (!(valid & (1u << i)))
                        w[i] = __hip_atomic_load(&bp[i], __ATOMIC_RELAXED, __HIP_MEMORY_SCOPE_AGENT);
                #pragma unroll
                for (int i = 0; i < 25; ++i)
                    if ((u32)(w[i] & 0xFFFFull) == (u32)tg) valid |= (1u << i);
            } while (valid != 0x1FFFFFFu);
        }
        ++r;

        bool anyviol = (__ballot(((w[24] >> 16) & 1ull) != 0ull) != 0ull);
        if (anyviol) {
            // rollback to pre-batch-(B-1) state and replay batch B-1 exactly
            #pragma unroll
            for (int e = 0; e < 16; ++e) md[e] = bku[e * 64 + lane];
            int sbase = 8 * (B - 1) + 1;
            for (int sub = 0; sub < 8; ++sub) { slow_round(r, sbase + sub); ++r; }
            pending = false;
            --B; continue;   // retry this exchange
        }
        if (B == 511) break; // batch 510 confirmed clean

        // ---- parse candidates (lane l holds block l's 8) ----
        float cpx[8], cpy[8], cpz[8], cmdf[8]; u32 cinv[8];
        #pragma unroll
        for (int c = 0; c < 8; ++c) {
            u64 a = w[3 * c], b = w[3 * c + 1], d = w[3 * c + 2];
            cpx[c] = __uint_as_float((u32)(a >> 32));
            cpy[c] = __uint_as_float((u32)(b >> 32));
            cpz[c] = __uint_as_float((u32)(d >> 32));
            cinv[c] = (u32)(a >> 16) & 0xFFFFu;
            u32 mdb = (((u32)(b >> 16) & 0xFFFFu) << 16) | ((u32)(d >> 16) & 0xFFFFu);
            cmdf[c] = __uint_as_float(mdb);
        }

        // ---- simulate 8 substeps over the 512-candidate union (identical in all blocks) ----
        u64 wk48[8]; float wxa[8], wya[8], wza[8];
        float pwx = 0.f, pwy = 0.f, pwz = 0.f;
        #pragma unroll
        for (int j = 0; j < 8; ++j) {
            if (j) {
                #pragma unroll
                for (int c = 0; c < 8; ++c)
                    cmdf[c] = fminf(cmdf[c], dist3(cpx[c], cpy[c], cpz[c], pwx, pwy, pwz));
            }
            u64 bk2 = 0; float b2x = 0.f, b2y = 0.f, b2z = 0.f;
            #pragma unroll
            for (int c = 0; c < 8; ++c) {
                u64 k = ((u64)__float_as_uint(cmdf[c]) << 16) | cinv[c];
                bool bt = k > bk2;
                bk2 = bt ? k : bk2; b2x = bt ? cpx[c] : b2x; b2y = bt ? cpy[c] : b2y; b2z = bt ? cpz[c] : b2z;
            }
            int src = wave_argmax48(bk2);
            u64 kw = __shfl(bk2, src);
            float wx = __shfl(b2x, src), wy = __shfl(b2y, src), wz = __shfl(b2z, src);
            wk48[j] = kw; wxa[j] = wx; wya[j] = wy; wza[j] = wz;
            pwx = wx; pwy = wy; pwz = wz;
            if (blk == 0 && lane == 0) id[8 * B + 1 + j] = (int)(0xFFFFu - (u32)(kw & 0xFFFFull));
        }

        // ---- snapshot, then verify + apply (exactness check incl. tie-break) ----
        #pragma unroll
        for (int e = 0; e < 16; ++e) bku[e * 64 + lane] = md[e];
        bool viol = false;
        #pragma unroll
        for (int j = 0; j < 8; ++j) {
            #pragma unroll
            for (int e = 0; e < 16; ++e) {
                u64 vk = ((u64)__float_as_uint(md[e]) << 16) | inv[e];
                viol |= (vk > wk48[j]);
            }
            #pragma unroll
            for (int e = 0; e < 16; ++e)
                md[e] = fminf(md[e], dist3(px[e], py[e], pz[e], wxa[j], wya[j], wza[j]));
        }
        pending = (__ballot(viol) != 0ull);
    }

    // final 7 steps: 4089..4095
    for (int s = 4089; s < 4096; ++s) { slow_round(r, s); ++r; }
}

// ---------------- sub_pos / sub_batch outputs ----------------
__global__ void subout_kernel(const float* __restrict__ pos, const int* __restrict__ batch,
                              const int* __restrict__ id, float* __restrict__ sub_pos,
                              int* __restrict__ sub_batch) {
    int m = blockIdx.x * blockDim.x + threadIdx.x;
    if (m >= MCLUS) return;
    int idx = id[m];
    sub_pos[m*3+0] = pos[idx*3+0];
    sub_pos[m*3+1] = pos[idx*3+1];
    sub_pos[m*3+2] = pos[idx*3+2];
    sub_batch[m] = batch[idx];
}

// ---------------- kNN: one wave per query ----------------
// d2 = (|q|^2 - 2*q.p) + |p|^2, all ops correctly-rounded, no FMA (match reference bits).
__global__ __launch_bounds__(64) void knn_kernel(const float* __restrict__ pos,
                                                 const int* __restrict__ id,
                                                 int* __restrict__ nbr) {
    const int q = blockIdx.x;
    const int lane = threadIdx.x;
    const int qi = id[q];
    const float qx = pos[qi*3+0], qy = pos[qi*3+1], qz = pos[qi*3+2];
    const float nq = __fadd_rn(__fadd_rn(__fmul_rn(qx,qx), __fmul_rn(qy,qy)), __fmul_rn(qz,qz));

    float dl[KNN]; int il[KNN];
    #pragma unroll
    for (int t = 0; t < KNN; ++t) { dl[t] = __builtin_inff(); il[t] = 0x7FFFFFFF; }

    for (int j = lane; j < N_PTS; j += 64) {
        float px = pos[j*3+0], py = pos[j*3+1], pz = pos[j*3+2];
        float npj = __fadd_rn(__fadd_rn(__fmul_rn(px,px), __fmul_rn(py,py)), __fmul_rn(pz,pz));
        float dot = __fadd_rn(__fadd_rn(__fmul_rn(qx,px), __fmul_rn(qy,py)), __fmul_rn(qz,pz));
        float d2  = __fadd_rn(__fsub_rn(nq, __fmul_rn(2.0f, dot)), npj);
        if (d2 < dl[KNN-1] || (d2 == dl[KNN-1] && j < il[KNN-1])) {
            dl[KNN-1] = d2; il[KNN-1] = j;
            #pragma unroll
            for (int t = KNN-1; t > 0; --t) {
                float a = dl[t-1], bq = dl[t];
                int   ai = il[t-1], bi = il[t];
                bool sw = (bq < a) || (bq == a && bi < ai);
                dl[t-1] = sw ? bq : a;  dl[t] = sw ? a : bq;
                il[t-1] = sw ? bi : ai; il[t] = sw ? ai : bi;
            }
        }
    }

    __shared__ float sd[64][KNN];
    __shared__ int   si[64][KNN];
    #pragma unroll
    for (int t = 0; t < KNN; ++t) { sd[lane][t] = dl[t]; si[lane][t] = il[t]; }
    __syncthreads();

    // 64-way merge of sorted lists: 16 rounds of wave-min over heads
    int ptr = 0;
    for (int rr = 0; rr < KNN; ++rr) {
        unsigned long long key = ~0ull;
        if (ptr < KNN) {
            unsigned u = __float_as_uint(sd[lane][ptr]);
            unsigned mu = (u >> 31) ? ~u : (u | 0x80000000u);   // order-preserving
            key = ((unsigned long long)mu << 32) | (unsigned)si[lane][ptr];
        }
        unsigned long long m = key;
        #pragma unroll
        for (int off = 32; off > 0; off >>= 1) {
            unsigned long long o = __shfl_xor(m, off);
            if (o < m) m = o;
        }
        if (key == m) ptr++;
        if (lane == 0) nbr[q*KNN + rr] = (int)(m & 0xFFFFFFFFull);
    }
}

// ---------------- BN stats: h = x@W + b, per-channel sum & sumsq ----------------
__global__ __launch_bounds__(256) void stats_kernel(const float* __restrict__ x,
                                                    const float* __restrict__ W,
                                                    const float* __restrict__ b,
                                                    float* __restrict__ psum,
                                                    float* __restrict__ psumsq) {
    __shared__ float xl[64*128];     // 32 KiB
    const int tid = threadIdx.x;
    const int cg = (tid & 63) * 4;   // channel group base
    const int rq = tid >> 6;         // row quarter (0..3)
    float s0=0,s1=0,s2v=0,s3=0, q0=0,q1=0,q2=0,q3=0;
    const float4 bv = *(const float4*)&b[cg];

    for (int t = 0; t < 2; ++t) {
        const size_t row0 = (size_t)blockIdx.x*128 + (size_t)t*64;
        __syncthreads();
        for (int i = tid*4; i < 64*128; i += 1024)
            *(float4*)&xl[i] = *(const float4*)&x[row0*128 + i];
        __syncthreads();

        float acc[16][4];
        #pragma unroll
        for (int rr = 0; rr < 16; ++rr) { acc[rr][0]=bv.x; acc[rr][1]=bv.y; acc[rr][2]=bv.z; acc[rr][3]=bv.w; }

        for (int k4 = 0; k4 < 32; ++k4) {
            float4 w0 = *(const float4*)&W[(k4*4+0)*256 + cg];
            float4 w1 = *(const float4*)&W[(k4*4+1)*256 + cg];
            float4 w2 = *(const float4*)&W[(k4*4+2)*256 + cg];
            float4 w3 = *(const float4*)&W[(k4*4+3)*256 + cg];
            #pragma unroll
            for (int rr = 0; rr < 16; ++rr) {
                float4 xv = *(float4*)&xl[(rq*16+rr)*128 + k4*4];
                acc[rr][0] = fmaf(xv.w,w3.x, fmaf(xv.z,w2.x, fmaf(xv.y,w1.x, fmaf(xv.x,w0.x, acc[rr][0]))));
                acc[rr][1] = fmaf(xv.w,w3.y, fmaf(xv.z,w2.y, fmaf(xv.y,w1.y, fmaf(xv.x,w0.y, acc[rr][1]))));
                acc[rr][2] = fmaf(xv.w,w3.z, fmaf(xv.z,w2.z, fmaf(xv.y,w1.z, fmaf(xv.x,w0.z, acc[rr][2]))));
                acc[rr][3] = fmaf(xv.w,w3.w, fmaf(xv.z,w2.w, fmaf(xv.y,w1.w, fmaf(xv.x,w0.w, acc[rr][3]))));
            }
        }
        #pragma unroll
        for (int rr = 0; rr < 16; ++rr) {
            s0 += acc[rr][0]; q0 = fmaf(acc[rr][0],acc[rr][0],q0);
            s1 += acc[rr][1]; q1 = fmaf(acc[rr][1],acc[rr][1],q1);
            s2v+= acc[rr][2]; q2 = fmaf(acc[rr][2],acc[rr][2],q2);
            s3 += acc[rr][3]; q3 = fmaf(acc[rr][3],acc[rr][3],q3);
        }
    }
    __syncthreads();
    float* red = xl;  // reuse
    red[rq*256 + cg+0] = s0; red[rq*256 + cg+1] = s1; red[rq*256 + cg+2] = s2v; red[rq*256 + cg+3] = s3;
    red[1024 + rq*256 + cg+0] = q0; red[1024 + rq*256 + cg+1] = q1;
    red[1024 + rq*256 + cg+2] = q2; red[1024 + rq*256 + cg+3] = q3;
    __syncthreads();
    if (rq == 0) {
        #pragma unroll
        for (int c = 0; c < 4; ++c) {
            int ch = cg + c;
            float ss = red[ch] + red[256+ch] + red[512+ch] + red[768+ch];
            float qq = red[1024+ch] + red[1280+ch] + red[1536+ch] + red[1792+ch];
            psum  [blockIdx.x*256 + ch] = ss;
            psumsq[blockIdx.x*256 + ch] = qq;
        }
    }
}

__global__ void finalize_kernel(const float* __restrict__ psum, const float* __restrict__ psumsq,
                                const float* __restrict__ gamma, const float* __restrict__ beta,
                                float* __restrict__ scale, float* __restrict__ shift) {
    int c = threadIdx.x;
    float s = 0.f, s2 = 0.f;
    for (int bl = 0; bl < 512; ++bl) { s += psum[bl*256+c]; s2 += psumsq[bl*256+c]; }
    float mu  = s  / 65536.0f;
    float var = s2 / 65536.0f - mu*mu;
    float inv = rsqrtf(var + 1e-5f);
    float sc = gamma[c] * inv;
    scale[c] = sc;
    shift[c] = beta[c] - mu * sc;
}

// ---------------- gather + recompute h rows + pooled BN/ReLU ----------------
__global__ __launch_bounds__(256) void out_kernel(const float* __restrict__ x,
                                                  const float* __restrict__ W,
                                                  const float* __restrict__ b,
                                                  const int* __restrict__ nbr,
                                                  const float* __restrict__ scale,
                                                  const float* __restrict__ shift,
                                                  float* __restrict__ out) {
    __shared__ float xl[16*128];   // 8 KiB
    __shared__ int nb[16];
    const int tid = threadIdx.x;
    const int m = blockIdx.x;
    if (tid < 16) nb[tid] = nbr[m*16 + tid];
    __syncthreads();
    for (int i = tid; i < 16*128; i += 256) {
        int rr = i >> 7, k = i & 127;
        xl[i] = x[(size_t)nb[rr]*128 + k];
    }
    __syncthreads();

    float acc[16];
    const float bias = b[tid];
    #pragma unroll
    for (int rr = 0; rr < 16; ++rr) acc[rr] = bias;

    for (int k4 = 0; k4 < 32; ++k4) {
        float w0 = W[(k4*4+0)*256 + tid];
        float w1 = W[(k4*4+1)*256 + tid];
        float w2 = W[(k4*4+2)*256 + tid];
        float w3 = W[(k4*4+3)*256 + tid];
        #pragma unroll
        for (int rr = 0; rr < 16; ++rr) {
            float4 xv = *(float4*)&xl[rr*128 + k4*4];
            acc[rr] = fmaf(xv.w,w3, fmaf(xv.z,w2, fmaf(xv.y,w1, fmaf(xv.x,w0, acc[rr]))));
        }
    }
    const float sc = scale[tid], sh = shift[tid];
    float v = acc[0];
    #pragma unroll
    for (int rr = 1; rr < 16; ++rr) v = (sc >= 0.f) ? fmaxf(v, acc[rr]) : fminf(v, acc[rr]);
    out[(size_t)m*256 + tid] = fmaxf(fmaf(sc, v, sh), 0.f);
}

// ---------------- launch ----------------
extern "C" void kernel_launch(void* const* d_in, const int* in_sizes, int n_in,
                              void* d_out, int out_size, void* d_ws, size_t ws_size,
                              hipStream_t stream) {
    const float* x     = (const float*)d_in[0];
    const float* pos   = (const float*)d_in[1];
    const int*   batch = (const int*)  d_in[2];
    const float* W     = (const float*)d_in[3];
    const float* b     = (const float*)d_in[4];
    const float* gamma = (const float*)d_in[5];
    const float* beta  = (const float*)d_in[6];

    float* out      = (float*)d_out;
    float* sub_pos  = out + (size_t)MCLUS*C_OUT;
    int*   sub_batch= (int*)(out + (size_t)MCLUS*C_OUT + (size_t)MCLUS*3);

    char* ws = (char*)d_ws;
    int* id        = (int*)(ws + WS_ID);
    u64* slots     = (u64*)(ws + WS_SLOTS);
    int* nbr       = (int*)(ws + WS_NBR);
    float* psum    = (float*)(ws + WS_PSUM);
    float* psumsq  = (float*)(ws + WS_PSUMSQ);
    float* scalep  = (float*)(ws + WS_SCALE);
    float* shiftp  = (float*)(ws + WS_SHIFT);

    init_kernel<<<1, 1024, 0, stream>>>(id, slots);
    fps_kernel<<<64, 64, 0, stream>>>(pos, id, slots);
    subout_kernel<<<16, 256, 0, stream>>>(pos, batch, id, sub_pos, sub_batch);
    knn_kernel<<<MCLUS, 64, 0, stream>>>(pos, id, nbr);
    stats_kernel<<<512, 256, 0, stream>>>(x, W, b, psum, psumsq);
    finalize_kernel<<<1, 256, 0, stream>>>(psum, psumsq, gamma, beta, scalep, shiftp);
    out_kernel<<<MCLUS, 256, 0, stream>>>(x, W, b, nbr, scalep, shiftp, out);
}